// Round 2
// baseline (2857.303 us; speedup 1.0000x reference)
//
#include <hip/hip_runtime.h>
#include <hip/hip_bf16.h>

// ---- problem constants ----
#define SEQLEN   1024
#define NTOK     2048          // BATCH * SEQLEN
#define DMODEL   1024
#define DSTATE   128
#define DINNER   2048
#define NHEADS   32
#define HEADDIM  64
#define CONVDIM  2304          // DINNER + 2*DSTATE
#define DINPROJ  4384          // 2*DINNER + 2*DSTATE + NHEADS
#define INTER    2752

// dual-dtype load: f32==1 -> fp32 array, else bf16 array
__device__ inline float ldv(const void* __restrict__ p, size_t i, int f32) {
    return f32 ? ((const float*)p)[i]
               : __bfloat162float(((const __hip_bfloat16*)p)[i]);
}

__device__ inline float block_reduce_sum(float v) {
    __shared__ float red[4];
    #pragma unroll
    for (int off = 32; off >= 1; off >>= 1) v += __shfl_down(v, off);
    int lane = threadIdx.x & 63, w = threadIdx.x >> 6;
    if (lane == 0) red[w] = v;
    __syncthreads();
    return red[0] + red[1] + red[2] + red[3];
}

// ---- dtype probe: flag=1 if hidden looks like fp32 misread as bf16 ----
__global__ __launch_bounds__(256) void detect_kernel(
    const void* __restrict__ hidden, int* __restrict__ flag)
{
    __shared__ int sbad;
    const __hip_bfloat16* hb = (const __hip_bfloat16*)hidden;
    if (threadIdx.x == 0) sbad = 0;
    __syncthreads();
    int bad = 0;
    for (int i = threadIdx.x; i < 4096; i += 256) {
        float v = __bfloat162float(hb[i]);
        if (!(fabsf(v) < 100.f)) bad = 1;   // catches huge AND NaN
    }
    if (bad) sbad = 1;                      // benign race
    __syncthreads();
    if (threadIdx.x == 0) *flag = sbad;
}

// ---- RMSNorm over 1024 dims; x_follows=1 -> x dtype per flag, else fp32 ----
__global__ __launch_bounds__(256) void rmsnorm1024_kernel(
    const void* __restrict__ x, const int x_follows,
    const void* __restrict__ w, const int* __restrict__ flagp,
    float* __restrict__ out)
{
    const int f32 = *flagp;
    const int xf = x_follows ? f32 : 1;
    const int token = blockIdx.x, t = threadIdx.x;
    float v[4]; float ss = 0.f;
    #pragma unroll
    for (int i = 0; i < 4; i++) {
        v[i] = ldv(x, (size_t)token * DMODEL + t * 4 + i, xf);
        ss += v[i] * v[i];
    }
    ss = block_reduce_sum(ss);
    const float scale = rsqrtf(ss * (1.0f / DMODEL) + 1e-6f);
    #pragma unroll
    for (int i = 0; i < 4; i++)
        out[(size_t)token * DMODEL + t * 4 + i] = v[i] * scale * ldv(w, t * 4 + i, f32);
}

// ---- C = A(MxK fp32) @ W(NxK flag-dtype)^T, 128x128 tile, 8x8/thread ----
// EPI 0: C=acc ; EPI 1: C=acc+resid(flag dtype) ; EPI 2: out=flagdtype(acc+f32resid)
template <int EPI>
__global__ __launch_bounds__(256) void gemm_bt(
    const float* __restrict__ A, const void* __restrict__ W,
    float* __restrict__ C, const void* __restrict__ resid_in,
    const float* __restrict__ resid_f, void* __restrict__ out_any,
    const int* __restrict__ flagp, int M, int N, int K)
{
    __shared__ float As[8][132];
    __shared__ float Ws[8][132];
    const int f32 = *flagp;
    const int tid = threadIdx.x;
    const int tx = tid & 15, ty = tid >> 4;
    const int m0 = blockIdx.y * 128, n0 = blockIdx.x * 128;
    const int lr = tid >> 1;        // 0..127 tile row for loading
    const int lk = (tid & 1) * 4;   // 0 or 4
    const float* Ap = A + (size_t)(m0 + lr) * K + lk;
    const bool wok = (n0 + lr) < N;
    const size_t wbase = (size_t)(wok ? (n0 + lr) : 0) * K + lk;

    float acc[8][8] = {};
    for (int k0 = 0; k0 < K; k0 += 8) {
        float av[4], wv[4];
        #pragma unroll
        for (int i = 0; i < 4; i++) av[i] = Ap[k0 + i];
        #pragma unroll
        for (int i = 0; i < 4; i++) wv[i] = wok ? ldv(W, wbase + k0 + i, f32) : 0.f;
        __syncthreads();
        #pragma unroll
        for (int i = 0; i < 4; i++) { As[lk + i][lr] = av[i]; Ws[lk + i][lr] = wv[i]; }
        __syncthreads();
        #pragma unroll
        for (int kk = 0; kk < 8; kk++) {
            float a[8], b[8];
            #pragma unroll
            for (int i = 0; i < 8; i++) a[i] = As[kk][ty * 8 + i];
            #pragma unroll
            for (int j = 0; j < 8; j++) b[j] = Ws[kk][tx * 8 + j];
            #pragma unroll
            for (int i = 0; i < 8; i++)
                #pragma unroll
                for (int j = 0; j < 8; j++)
                    acc[i][j] += a[i] * b[j];
        }
    }
    #pragma unroll
    for (int i = 0; i < 8; i++) {
        const int m = m0 + ty * 8 + i;
        #pragma unroll
        for (int j = 0; j < 8; j++) {
            const int n = n0 + tx * 8 + j;
            if (n < N) {
                const size_t idx = (size_t)m * N + n;
                float v = acc[i][j];
                if (EPI == 2) {
                    v += resid_f[idx];
                    if (f32) ((float*)out_any)[idx] = v;
                    else ((__hip_bfloat16*)out_any)[idx] = __float2bfloat16(v);
                } else {
                    if (EPI == 1) v += ldv(resid_in, idx, f32);
                    C[idx] = v;
                }
            }
        }
    }
}

// ---- depthwise causal conv (k=4) + bias + silu over xBC channels ----
__global__ __launch_bounds__(256) void conv_silu_kernel(
    const float* __restrict__ zx, const void* __restrict__ cw,
    const void* __restrict__ cb, const int* __restrict__ flagp,
    float* __restrict__ out)
{
    const int f32 = *flagp;
    const int idx = blockIdx.x * 256 + threadIdx.x;
    if (idx >= NTOK * CONVDIM) return;
    const int c = idx % CONVDIM;
    const int token = idx / CONVDIM;
    const int l = token & (SEQLEN - 1);
    float acc = ldv(cb, c, f32);
    #pragma unroll
    for (int k = 0; k < 4; k++) {
        const int ls = l - 3 + k;
        if (ls >= 0)
            acc += zx[(size_t)(token - 3 + k) * DINPROJ + DINNER + c] * ldv(cw, c * 4 + k, f32);
    }
    out[(size_t)token * CONVDIM + c] = acc / (1.f + expf(-acc));   // silu
}

// ---- dt = softplus(dt_raw + dt_bias) ----
__global__ __launch_bounds__(256) void dt_softplus_kernel(
    const float* __restrict__ zx, const void* __restrict__ dtb,
    const int* __restrict__ flagp, float* __restrict__ out)
{
    const int f32 = *flagp;
    const int idx = blockIdx.x * 256 + threadIdx.x;   // NTOK*NHEADS
    const int h = idx & (NHEADS - 1);
    const int token = idx >> 5;
    float v = zx[(size_t)token * DINPROJ + (DINNER + CONVDIM) + h] + ldv(dtb, h, f32);
    out[idx] = (v > 20.f) ? v : log1pf(expf(v));
}

// ---- selective scan: one block per (batch, head); state 64x128 in regs ----
__global__ __launch_bounds__(256) void scan_kernel(
    const float* __restrict__ convb, const float* __restrict__ dtb,
    const void* __restrict__ A_log, const void* __restrict__ Dh,
    const int* __restrict__ flagp, float* __restrict__ y)
{
    const int f32 = *flagp;
    const int b = blockIdx.x >> 5;
    const int h = blockIdx.x & 31;
    const int t = threadIdx.x;
    const int p = t >> 2;       // 0..63 head dim
    const int q = t & 3;        // quad: 32 states each
    const float A = -expf(ldv(A_log, h, f32));
    const float Dv = ldv(Dh, h, f32);
    float hs[32];
    #pragma unroll
    for (int j = 0; j < 32; j++) hs[j] = 0.f;

    __shared__ float sB[DSTATE], sC[DSTATE];
    const float* base = convb + (size_t)b * SEQLEN * CONVDIM;
    const float* dtp = dtb + (size_t)b * SEQLEN * NHEADS + h;
    float* yb = y + (size_t)b * SEQLEN * DINNER + h * HEADDIM + p;
    const int n0 = q * 32;

    for (int l = 0; l < SEQLEN; l++) {
        const float* tok = base + (size_t)l * CONVDIM;
        __syncthreads();
        if (t < 128) sB[t] = tok[DINNER + t];
        else         sC[t - 128] = tok[DINNER + t];
        __syncthreads();
        const float dt_t = dtp[l * NHEADS];
        const float dA = expf(dt_t * A);
        const float x_p = tok[h * HEADDIM + p];
        const float coef = dt_t * x_p;
        float ysum = 0.f;
        #pragma unroll
        for (int j = 0; j < 32; j++) {
            float hv = hs[j] * dA + coef * sB[n0 + j];
            hs[j] = hv;
            ysum += hv * sC[n0 + j];
        }
        ysum += __shfl_xor(ysum, 1);
        ysum += __shfl_xor(ysum, 2);
        if (q == 0) yb[(size_t)l * DINNER] = ysum + Dv * x_p;
    }
}

// ---- ynorm = rmsnorm(y * silu(z)) over 2048 dims ----
__global__ __launch_bounds__(256) void gated_rmsnorm_kernel(
    const float* __restrict__ y, const float* __restrict__ zx,
    const void* __restrict__ w, const int* __restrict__ flagp,
    float* __restrict__ out)
{
    const int f32 = *flagp;
    const int token = blockIdx.x, t = threadIdx.x;
    const float* yr = y + (size_t)token * DINNER;
    const float* zr = zx + (size_t)token * DINPROJ;   // z = first 2048
    float v[8]; float ss = 0.f;
    #pragma unroll
    for (int i = 0; i < 8; i++) {
        const int idx = t * 8 + i;
        const float zz = zr[idx];
        const float val = yr[idx] * (zz / (1.f + expf(-zz)));
        v[i] = val; ss += val * val;
    }
    ss = block_reduce_sum(ss);
    const float scale = rsqrtf(ss * (1.0f / DINNER) + 1e-6f);
    #pragma unroll
    for (int i = 0; i < 8; i++) {
        const int idx = t * 8 + i;
        out[(size_t)token * DINNER + idx] = v[i] * scale * ldv(w, idx, f32);
    }
}

// ---- act = silu(g) * u (in place into g) ----
__global__ __launch_bounds__(256) void silu_mul_kernel(
    float* __restrict__ g, const float* __restrict__ u, int n)
{
    const int i = blockIdx.x * 256 + threadIdx.x;
    if (i < n) {
        const float gv = g[i];
        g[i] = (gv / (1.f + expf(-gv))) * u[i];
    }
}

extern "C" void kernel_launch(void* const* d_in, const int* in_sizes, int n_in,
                              void* d_out, int out_size, void* d_ws, size_t ws_size,
                              hipStream_t stream) {
    const void* hidden     = d_in[0];
    const void* norm_w     = d_in[1];
    const void* in_proj_w  = d_in[2];
    const void* conv_w     = d_in[3];
    const void* conv_b     = d_in[4];
    const void* dt_bias    = d_in[5];
    const void* A_log      = d_in[6];
    const void* Dh         = d_in[7];
    const void* ssm_norm_w = d_in[8];
    const void* out_proj_w = d_in[9];
    const void* post_norm_w= d_in[10];
    const void* gate_w     = d_in[11];
    const void* up_w       = d_in[12];
    const void* down_w     = d_in[13];

    float* ws = (float*)d_ws;
    int*   flag   = (int*)d_ws;         // [0,16) floats reserved
    float* h_norm = ws + 16;            // 2048*1024   = 2,097,152
    float* zx     = ws + 2097168;       // 2048*4384   = 8,978,432
    float* convb  = ws + 11075600;      // 2048*2304   = 4,718,592
    float* dtb    = ws + 15794192;      // 2048*32     = 65,536
    float* ybuf   = ws + 15859728;      // 2048*2048   = 4,194,304
    float* xbuf   = ws + 21495824;      // 2048*1024   = 2,097,152  (after ubuf)
    float* ynorm  = convb;              // reuse (convb consumed by scan)
    float* h2     = h_norm;             // reuse (h_norm consumed by in_proj)
    float* gbuf   = zx;                 // reuse (zx consumed by step 6): 5,636,096
    float* ubuf   = ybuf;               // reuse (ybuf consumed by step 6): 5,636,096
    // total ws: 23,592,976 floats = 94.4 MB

    // 0. dtype probe
    detect_kernel<<<1, 256, 0, stream>>>(hidden, flag);
    // 1. h = rmsnorm(hidden, norm_w)
    rmsnorm1024_kernel<<<NTOK, 256, 0, stream>>>(hidden, 1, norm_w, flag, h_norm);
    // 2. zxbcdt = h @ in_proj_w^T   (2048 x 4384)
    gemm_bt<0><<<dim3(35, 16), 256, 0, stream>>>(h_norm, in_proj_w, zx,
        nullptr, nullptr, nullptr, flag, NTOK, DINPROJ, DMODEL);
    // 3. conv(k=4) + bias + silu on xBC
    conv_silu_kernel<<<(NTOK * CONVDIM) / 256, 256, 0, stream>>>(zx, conv_w, conv_b, flag, convb);
    // 4. dt = softplus(dt_raw + dt_bias)
    dt_softplus_kernel<<<(NTOK * NHEADS) / 256, 256, 0, stream>>>(zx, dt_bias, flag, dtb);
    // 5. selective scan -> y (+ D*x)
    scan_kernel<<<2 * NHEADS, 256, 0, stream>>>(convb, dtb, A_log, Dh, flag, ybuf);
    // 6. ynorm = rmsnorm(y * silu(z), ssm_norm_w)
    gated_rmsnorm_kernel<<<NTOK, 256, 0, stream>>>(ybuf, zx, ssm_norm_w, flag, ynorm);
    // 7. x = hidden + ynorm @ out_proj_w^T
    gemm_bt<1><<<dim3(8, 16), 256, 0, stream>>>(ynorm, out_proj_w, xbuf,
        hidden, nullptr, nullptr, flag, NTOK, DMODEL, DINNER);
    // 8. h2 = rmsnorm(x, post_norm_w)   (x is fp32 ws -> x_follows=0)
    rmsnorm1024_kernel<<<NTOK, 256, 0, stream>>>(xbuf, 0, post_norm_w, flag, h2);
    // 9. g = h2 @ gate_w^T ; u = h2 @ up_w^T
    gemm_bt<0><<<dim3(22, 16), 256, 0, stream>>>(h2, gate_w, gbuf,
        nullptr, nullptr, nullptr, flag, NTOK, INTER, DMODEL);
    gemm_bt<0><<<dim3(22, 16), 256, 0, stream>>>(h2, up_w, ubuf,
        nullptr, nullptr, nullptr, flag, NTOK, INTER, DMODEL);
    // 10. act = silu(g) * u
    silu_mul_kernel<<<(NTOK * INTER) / 256, 256, 0, stream>>>(gbuf, ubuf, NTOK * INTER);
    // 11. out = x + act @ down_w^T   (dtype per flag)
    gemm_bt<2><<<dim3(8, 16), 256, 0, stream>>>(gbuf, down_w, nullptr,
        nullptr, xbuf, d_out, flag, NTOK, DMODEL, INTER);
}

// Round 6
// 1176.044 us; speedup vs baseline: 2.4296x; 2.4296x over previous
//
#include <hip/hip_runtime.h>
#include <hip/hip_bf16.h>

// ---- problem constants ----
#define SEQLEN   1024
#define NTOK     2048          // BATCH * SEQLEN
#define DMODEL   1024
#define DSTATE   128
#define DINNER   2048
#define NHEADS   32
#define HEADDIM  64
#define CONVDIM  2304          // DINNER + 2*DSTATE
#define DINPROJ  4384          // 2*DINNER + 2*DSTATE + NHEADS
#define INTER    2752

typedef __hip_bfloat16 bf16;
typedef unsigned short ushort_t;
typedef __attribute__((ext_vector_type(8))) short bf16x8;
typedef __attribute__((ext_vector_type(4))) float f32x4;

__device__ __forceinline__ float bf2f(bf16 x) { return __bfloat162float(x); }

__device__ __forceinline__ bf16x8 cvt8(f32x4 a, f32x4 b) {
    union { bf16x8 v; bf16 e[8]; } u;
    #pragma unroll
    for (int i = 0; i < 4; i++) {
        u.e[i]     = __float2bfloat16(a[i]);
        u.e[4 + i] = __float2bfloat16(b[i]);
    }
    return u.v;
}

__device__ inline float block_reduce_sum(float v) {
    __shared__ float red[4];
    #pragma unroll
    for (int off = 32; off >= 1; off >>= 1) v += __shfl_down(v, off);
    int lane = threadIdx.x & 63, w = threadIdx.x >> 6;
    if (lane == 0) red[w] = v;
    __syncthreads();
    return red[0] + red[1] + red[2] + red[3];
}

// ---- RMSNorm over 1024 dims (fp32 in, fp32 weights) -> bf16 out ----
__global__ __launch_bounds__(256) void rmsnorm1024_kernel(
    const float* __restrict__ x, const float* __restrict__ w, bf16* __restrict__ out)
{
    const int token = blockIdx.x, t = threadIdx.x;
    float v[4]; float ss = 0.f;
    #pragma unroll
    for (int i = 0; i < 4; i++) {
        v[i] = x[(size_t)token * DMODEL + t * 4 + i];
        ss += v[i] * v[i];
    }
    ss = block_reduce_sum(ss);
    const float scale = rsqrtf(ss * (1.0f / DMODEL) + 1e-6f);
    #pragma unroll
    for (int i = 0; i < 4; i++)
        out[(size_t)token * DMODEL + t * 4 + i] =
            __float2bfloat16(v[i] * scale * w[t * 4 + i]);
}

// ---- MFMA GEMM: C(MxN f32) = A(MxK bf16) @ W(NxK f32->bf16)^T ----
// 128x128 tile, BK=32, 256 thr (4 waves, 2x2 of 64x64), 16x16x32 MFMA
// Staging: explicit global loads -> regs (cvt W to bf16) -> ds_write_b128
// EPI 0: Cf=acc ; EPI 1: Cf=acc+resid_f
template <int EPI>
__global__ __launch_bounds__(256) void gemm_mfma(
    const bf16* __restrict__ A, const float* __restrict__ W,
    float* __restrict__ Cf, const float* __restrict__ resid_f,
    int M, int N, int K)
{
    __shared__ ushort_t As[128 * 32];
    __shared__ ushort_t Bs[128 * 32];
    const int tid = threadIdx.x;
    const int w = tid >> 6, lane = tid & 63;
    const int m0 = blockIdx.y * 128, n0 = blockIdx.x * 128;

    // staging map: thread covers rows srow and srow+64, k-chunk skof..skof+8
    const int srow = tid >> 2;
    const int skof = (tid & 3) * 8;
    const bf16* Ag0 = A + (size_t)(m0 + srow) * K + skof;
    const bf16* Ag1 = Ag0 + (size_t)64 * K;
    const int nr0 = n0 + srow, nr1 = n0 + 64 + srow;
    const float* Wg0 = W + (size_t)(nr0 < N ? nr0 : 0) * K + skof;  // clamp OOB row
    const float* Wg1 = W + (size_t)(nr1 < N ? nr1 : 0) * K + skof;

    const int wy = w >> 1, wx = w & 1;
    const int fr = lane & 15;              // fragment row (m or n)
    const int fk = (lane >> 4) * 8;        // fragment k offset
    f32x4 acc[4][4];
    #pragma unroll
    for (int i = 0; i < 4; i++)
        #pragma unroll
        for (int j = 0; j < 4; j++)
            acc[i][j] = (f32x4){0.f, 0.f, 0.f, 0.f};

    for (int k0 = 0; k0 < K; k0 += 32) {
        const bf16x8 av0 = *(const bf16x8*)(Ag0 + k0);
        const bf16x8 av1 = *(const bf16x8*)(Ag1 + k0);
        const f32x4 w00 = *(const f32x4*)(Wg0 + k0);
        const f32x4 w01 = *(const f32x4*)(Wg0 + k0 + 4);
        const f32x4 w10 = *(const f32x4*)(Wg1 + k0);
        const f32x4 w11 = *(const f32x4*)(Wg1 + k0 + 4);
        const bf16x8 wv0 = cvt8(w00, w01);
        const bf16x8 wv1 = cvt8(w10, w11);
        __syncthreads();                   // prev iter's LDS reads done
        *(bf16x8*)&As[srow * 32 + skof]        = av0;
        *(bf16x8*)&As[(64 + srow) * 32 + skof] = av1;
        *(bf16x8*)&Bs[srow * 32 + skof]        = wv0;
        *(bf16x8*)&Bs[(64 + srow) * 32 + skof] = wv1;
        __syncthreads();                   // stores visible to all waves
        bf16x8 af[4], bfv[4];
        #pragma unroll
        for (int i = 0; i < 4; i++)
            af[i] = *(const bf16x8*)&As[(wy * 64 + i * 16 + fr) * 32 + fk];
        #pragma unroll
        for (int j = 0; j < 4; j++)
            bfv[j] = *(const bf16x8*)&Bs[(wx * 64 + j * 16 + fr) * 32 + fk];
        #pragma unroll
        for (int i = 0; i < 4; i++)
            #pragma unroll
            for (int j = 0; j < 4; j++)
                acc[i][j] = __builtin_amdgcn_mfma_f32_16x16x32_bf16(
                    af[i], bfv[j], acc[i][j], 0, 0, 0);
    }

    // C/D layout: col = lane&15, row = (lane>>4)*4 + reg
    #pragma unroll
    for (int i = 0; i < 4; i++) {
        #pragma unroll
        for (int j = 0; j < 4; j++) {
            const int mb = m0 + wy * 64 + i * 16 + (lane >> 4) * 4;
            const int nn = n0 + wx * 64 + j * 16 + (lane & 15);
            if (nn < N) {
                #pragma unroll
                for (int r = 0; r < 4; r++) {
                    const size_t idx = (size_t)(mb + r) * N + nn;
                    float v = acc[i][j][r];
                    if (EPI == 1) v += resid_f[idx];
                    Cf[idx] = v;
                }
            }
        }
    }
}

// ---- depthwise causal conv (k=4) + bias + silu over xBC channels ----
__global__ __launch_bounds__(256) void conv_silu_kernel(
    const float* __restrict__ zx, const float* __restrict__ cw,
    const float* __restrict__ cb, float* __restrict__ out)
{
    const int idx = blockIdx.x * 256 + threadIdx.x;
    if (idx >= NTOK * CONVDIM) return;
    const int c = idx % CONVDIM;
    const int token = idx / CONVDIM;
    const int l = token & (SEQLEN - 1);
    float acc = cb[c];
    #pragma unroll
    for (int k = 0; k < 4; k++) {
        const int ls = l - 3 + k;
        if (ls >= 0)
            acc += zx[(size_t)(token - 3 + k) * DINPROJ + DINNER + c] * cw[c * 4 + k];
    }
    out[(size_t)token * CONVDIM + c] = acc / (1.f + expf(-acc));   // silu
}

// ---- dt = softplus(dt_raw + dt_bias) ----
__global__ __launch_bounds__(256) void dt_softplus_kernel(
    const float* __restrict__ zx, const float* __restrict__ dtb,
    float* __restrict__ out)
{
    const int idx = blockIdx.x * 256 + threadIdx.x;   // NTOK*NHEADS
    const int h = idx & (NHEADS - 1);
    const int token = idx >> 5;
    float v = zx[(size_t)token * DINPROJ + (DINNER + CONVDIM) + h] + dtb[h];
    out[idx] = (v > 20.f) ? v : log1pf(expf(v));
}

// ---- selective scan with register prefetch: one block per (batch, head) ----
__global__ __launch_bounds__(256) void scan_kernel(
    const float* __restrict__ convb, const float* __restrict__ dtb,
    const float* __restrict__ A_log, const float* __restrict__ Dh,
    float* __restrict__ y)
{
    const int b = blockIdx.x >> 5;
    const int h = blockIdx.x & 31;
    const int t = threadIdx.x;
    const int p = t >> 2;       // 0..63 head dim
    const int q = t & 3;        // quad: 32 states each
    const float A = -expf(A_log[h]);
    const float Dv = Dh[h];
    float hs[32];
    #pragma unroll
    for (int j = 0; j < 32; j++) hs[j] = 0.f;

    __shared__ float sBC[256];          // [0,128)=B, [128,256)=C
    const float* base = convb + (size_t)b * SEQLEN * CONVDIM;
    const float* dtp = dtb + (size_t)b * SEQLEN * NHEADS + h;
    float* yb = y + (size_t)b * SEQLEN * DINNER + h * HEADDIM + p;
    const int n0 = q * 32;

    // prefetch l=0
    float vBC = base[DINNER + t];
    float xp  = base[h * HEADDIM + p];
    float dtv = dtp[0];

    for (int l = 0; l < SEQLEN; l++) {
        sBC[t] = vBC;
        __syncthreads();
        // prefetch l+1 (clamped) — latency overlaps compute below
        const int ln = (l + 1 < SEQLEN) ? (l + 1) : (SEQLEN - 1);
        const float* ntok = base + (size_t)ln * CONVDIM;
        const float nBC = ntok[DINNER + t];
        const float nxp = ntok[h * HEADDIM + p];
        const float ndt = dtp[(size_t)ln * NHEADS];

        const float dA = expf(dtv * A);
        const float coef = dtv * xp;
        float ysum = 0.f;
        #pragma unroll
        for (int j = 0; j < 32; j++) {
            float hv = hs[j] * dA + coef * sBC[n0 + j];
            hs[j] = hv;
            ysum += hv * sBC[128 + n0 + j];
        }
        ysum += __shfl_xor(ysum, 1);
        ysum += __shfl_xor(ysum, 2);
        if (q == 0) yb[(size_t)l * DINNER] = ysum + Dv * xp;
        __syncthreads();
        vBC = nBC; xp = nxp; dtv = ndt;
    }
}

// ---- ynorm = rmsnorm(y * silu(z)) over 2048 dims -> bf16 ----
__global__ __launch_bounds__(256) void gated_rmsnorm_kernel(
    const float* __restrict__ y, const float* __restrict__ zx,
    const float* __restrict__ w, bf16* __restrict__ out)
{
    const int token = blockIdx.x, t = threadIdx.x;
    const float* yr = y + (size_t)token * DINNER;
    const float* zr = zx + (size_t)token * DINPROJ;   // z = first 2048
    float v[8]; float ss = 0.f;
    #pragma unroll
    for (int i = 0; i < 8; i++) {
        const int idx = t * 8 + i;
        const float zz = zr[idx];
        const float val = yr[idx] * (zz / (1.f + expf(-zz)));
        v[i] = val; ss += val * val;
    }
    ss = block_reduce_sum(ss);
    const float scale = rsqrtf(ss * (1.0f / DINNER) + 1e-6f);
    #pragma unroll
    for (int i = 0; i < 8; i++) {
        const int idx = t * 8 + i;
        out[(size_t)token * DINNER + idx] =
            __float2bfloat16(v[i] * scale * w[idx]);
    }
}

// ---- act = bf16(silu(g) * u) ----
__global__ __launch_bounds__(256) void silu_mul_kernel(
    const float* __restrict__ g, const float* __restrict__ u,
    bf16* __restrict__ act, int n)
{
    const int i = blockIdx.x * 256 + threadIdx.x;
    if (i < n) {
        const float gv = g[i];
        act[i] = __float2bfloat16((gv / (1.f + expf(-gv))) * u[i]);
    }
}

extern "C" void kernel_launch(void* const* d_in, const int* in_sizes, int n_in,
                              void* d_out, int out_size, void* d_ws, size_t ws_size,
                              hipStream_t stream) {
    const float* hidden     = (const float*)d_in[0];
    const float* norm_w     = (const float*)d_in[1];
    const float* in_proj_w  = (const float*)d_in[2];
    const float* conv_w     = (const float*)d_in[3];
    const float* conv_b     = (const float*)d_in[4];
    const float* dt_bias    = (const float*)d_in[5];
    const float* A_log      = (const float*)d_in[6];
    const float* Dh         = (const float*)d_in[7];
    const float* ssm_norm_w = (const float*)d_in[8];
    const float* out_proj_w = (const float*)d_in[9];
    const float* post_norm_w= (const float*)d_in[10];
    const float* gate_w     = (const float*)d_in[11];
    const float* up_w       = (const float*)d_in[12];
    const float* down_w     = (const float*)d_in[13];
    float* out = (float*)d_out;

    // ---- workspace layout (float slots; peak = 21,102,592 fl = 84.4 MB) ----
    float* ws = (float*)d_ws;
    bf16*  h_norm = (bf16*)(ws);            // [0, 1,048,576)        bf16 2048x1024
    float* zx     = ws + 1048576;           // [1,048,576, 10,027,008)   2048x4384
    float* ybuf   = ws + 10027008;          // [10,027,008, 14,221,312)  2048x2048
    float* convb  = ws + 14221312;          // [14,221,312, 18,939,904)  2048x2304
    float* dtb    = ws + 18939904;          // [18,939,904, 19,005,440)  2048x32
    float* xbuf   = ws + 19005440;          // [19,005,440, 21,102,592)  2048x1024
    bf16*  ynorm  = (bf16*)convb;           // reuse: convb dead after scan
    bf16*  h2     = h_norm;                 // reuse: h_norm dead after in_proj
    float* gbuf   = ws + 1048576;           // reuse zx (dead after step 6)
    float* ubuf   = ws + 6684672;           // reuse zx tail + ybuf (dead)
    bf16*  act    = (bf16*)convb;           // reuse: ynorm dead after out_proj

    // 1. h = rmsnorm(hidden, norm_w)  -> bf16
    rmsnorm1024_kernel<<<NTOK, 256, 0, stream>>>(hidden, norm_w, h_norm);
    // 2. zxbcdt = h @ in_proj_w^T   (2048 x 4384, f32 out)
    gemm_mfma<0><<<dim3(35, 16), 256, 0, stream>>>(h_norm, in_proj_w, zx,
        nullptr, NTOK, DINPROJ, DMODEL);
    // 3. conv(k=4) + bias + silu on xBC
    conv_silu_kernel<<<(NTOK * CONVDIM) / 256, 256, 0, stream>>>(zx, conv_w, conv_b, convb);
    // 4. dt = softplus(dt_raw + dt_bias)
    dt_softplus_kernel<<<(NTOK * NHEADS) / 256, 256, 0, stream>>>(zx, dt_bias, dtb);
    // 5. selective scan -> y (+ D*x)
    scan_kernel<<<2 * NHEADS, 256, 0, stream>>>(convb, dtb, A_log, Dh, ybuf);
    // 6. ynorm = rmsnorm(y * silu(z), ssm_norm_w)  -> bf16
    gated_rmsnorm_kernel<<<NTOK, 256, 0, stream>>>(ybuf, zx, ssm_norm_w, ynorm);
    // 7. x = hidden + ynorm @ out_proj_w^T  (f32)
    gemm_mfma<1><<<dim3(8, 16), 256, 0, stream>>>(ynorm, out_proj_w, xbuf,
        hidden, NTOK, DMODEL, DINNER);
    // 8. h2 = rmsnorm(x, post_norm_w)  -> bf16
    rmsnorm1024_kernel<<<NTOK, 256, 0, stream>>>(xbuf, post_norm_w, h2);
    // 9. g = h2 @ gate_w^T ; u = h2 @ up_w^T  (f32)
    gemm_mfma<0><<<dim3(22, 16), 256, 0, stream>>>(h2, gate_w, gbuf,
        nullptr, NTOK, INTER, DMODEL);
    gemm_mfma<0><<<dim3(22, 16), 256, 0, stream>>>(h2, up_w, ubuf,
        nullptr, NTOK, INTER, DMODEL);
    // 10. act = bf16(silu(g) * u)
    silu_mul_kernel<<<(NTOK * INTER) / 256, 256, 0, stream>>>(gbuf, ubuf, act, NTOK * INTER);
    // 11. out = x + act @ down_w^T   (f32 to d_out)
    gemm_mfma<1><<<dim3(8, 16), 256, 0, stream>>>(act, down_w, out,
        xbuf, NTOK, DMODEL, INTER);
}

// Round 7
// 611.974 us; speedup vs baseline: 4.6690x; 1.9217x over previous
//
#include <hip/hip_runtime.h>
#include <hip/hip_bf16.h>

// ---- problem constants ----
#define SEQLEN   1024
#define NTOK     2048          // BATCH * SEQLEN
#define DMODEL   1024
#define DSTATE   128
#define DINNER   2048
#define NHEADS   32
#define HEADDIM  64
#define CONVDIM  2304          // DINNER + 2*DSTATE
#define DINPROJ  4384          // 2*DINNER + 2*DSTATE + NHEADS
#define INTER    2752
#define Q        64            // scan chunk length
#define NCHUNK   16            // SEQLEN / Q

typedef __hip_bfloat16 bf16;
typedef unsigned short ushort_t;
typedef __attribute__((ext_vector_type(8))) short bf16x8;
typedef __attribute__((ext_vector_type(4))) float f32x4;
typedef __attribute__((ext_vector_type(4))) unsigned short u16x4;

__device__ __forceinline__ float bf2f(bf16 x) { return __bfloat162float(x); }
__device__ __forceinline__ float bfu2f(ushort_t u) {
    return __uint_as_float(((unsigned)u) << 16);
}
__device__ __forceinline__ ushort_t f2bfu(float x) {
    union { bf16 h; ushort_t u; } c; c.h = __float2bfloat16(x); return c.u;
}
__device__ __forceinline__ unsigned packbf2(float x, float y) {
    return ((unsigned)f2bfu(y) << 16) | f2bfu(x);
}

__device__ __forceinline__ bf16x8 cvt8(f32x4 a, f32x4 b) {
    union { bf16x8 v; bf16 e[8]; } u;
    #pragma unroll
    for (int i = 0; i < 4; i++) {
        u.e[i]     = __float2bfloat16(a[i]);
        u.e[4 + i] = __float2bfloat16(b[i]);
    }
    return u.v;
}

__device__ inline float block_reduce_sum(float v) {
    __shared__ float red[4];
    #pragma unroll
    for (int off = 32; off >= 1; off >>= 1) v += __shfl_down(v, off);
    int lane = threadIdx.x & 63, w = threadIdx.x >> 6;
    if (lane == 0) red[w] = v;
    __syncthreads();
    return red[0] + red[1] + red[2] + red[3];
}

// ---- RMSNorm over 1024 dims (fp32 in, fp32 weights) -> bf16 out ----
__global__ __launch_bounds__(256) void rmsnorm1024_kernel(
    const float* __restrict__ x, const float* __restrict__ w, bf16* __restrict__ out)
{
    const int token = blockIdx.x, t = threadIdx.x;
    float v[4]; float ss = 0.f;
    #pragma unroll
    for (int i = 0; i < 4; i++) {
        v[i] = x[(size_t)token * DMODEL + t * 4 + i];
        ss += v[i] * v[i];
    }
    ss = block_reduce_sum(ss);
    const float scale = rsqrtf(ss * (1.0f / DMODEL) + 1e-6f);
    #pragma unroll
    for (int i = 0; i < 4; i++)
        out[(size_t)token * DMODEL + t * 4 + i] =
            __float2bfloat16(v[i] * scale * w[t * 4 + i]);
}

// ---- MFMA GEMM: C(MxN f32) = A(MxK bf16) @ W(NxK f32->bf16)^T ----
template <int EPI>
__global__ __launch_bounds__(256) void gemm_mfma(
    const bf16* __restrict__ A, const float* __restrict__ W,
    float* __restrict__ Cf, const float* __restrict__ resid_f,
    int M, int N, int K)
{
    __shared__ ushort_t As[128 * 32];
    __shared__ ushort_t Bs[128 * 32];
    const int tid = threadIdx.x;
    const int w = tid >> 6, lane = tid & 63;
    const int m0 = blockIdx.y * 128, n0 = blockIdx.x * 128;

    const int srow = tid >> 2;
    const int skof = (tid & 3) * 8;
    const bf16* Ag0 = A + (size_t)(m0 + srow) * K + skof;
    const bf16* Ag1 = Ag0 + (size_t)64 * K;
    const int nr0 = n0 + srow, nr1 = n0 + 64 + srow;
    const float* Wg0 = W + (size_t)(nr0 < N ? nr0 : 0) * K + skof;
    const float* Wg1 = W + (size_t)(nr1 < N ? nr1 : 0) * K + skof;

    const int wy = w >> 1, wx = w & 1;
    const int fr = lane & 15;
    const int fk = (lane >> 4) * 8;
    f32x4 acc[4][4];
    #pragma unroll
    for (int i = 0; i < 4; i++)
        #pragma unroll
        for (int j = 0; j < 4; j++)
            acc[i][j] = (f32x4){0.f, 0.f, 0.f, 0.f};

    for (int k0 = 0; k0 < K; k0 += 32) {
        const bf16x8 av0 = *(const bf16x8*)(Ag0 + k0);
        const bf16x8 av1 = *(const bf16x8*)(Ag1 + k0);
        const f32x4 w00 = *(const f32x4*)(Wg0 + k0);
        const f32x4 w01 = *(const f32x4*)(Wg0 + k0 + 4);
        const f32x4 w10 = *(const f32x4*)(Wg1 + k0);
        const f32x4 w11 = *(const f32x4*)(Wg1 + k0 + 4);
        const bf16x8 wv0 = cvt8(w00, w01);
        const bf16x8 wv1 = cvt8(w10, w11);
        __syncthreads();
        *(bf16x8*)&As[srow * 32 + skof]        = av0;
        *(bf16x8*)&As[(64 + srow) * 32 + skof] = av1;
        *(bf16x8*)&Bs[srow * 32 + skof]        = wv0;
        *(bf16x8*)&Bs[(64 + srow) * 32 + skof] = wv1;
        __syncthreads();
        bf16x8 af[4], bfv[4];
        #pragma unroll
        for (int i = 0; i < 4; i++)
            af[i] = *(const bf16x8*)&As[(wy * 64 + i * 16 + fr) * 32 + fk];
        #pragma unroll
        for (int j = 0; j < 4; j++)
            bfv[j] = *(const bf16x8*)&Bs[(wx * 64 + j * 16 + fr) * 32 + fk];
        #pragma unroll
        for (int i = 0; i < 4; i++)
            #pragma unroll
            for (int j = 0; j < 4; j++)
                acc[i][j] = __builtin_amdgcn_mfma_f32_16x16x32_bf16(
                    af[i], bfv[j], acc[i][j], 0, 0, 0);
    }

    #pragma unroll
    for (int i = 0; i < 4; i++) {
        #pragma unroll
        for (int j = 0; j < 4; j++) {
            const int mb = m0 + wy * 64 + i * 16 + (lane >> 4) * 4;
            const int nn = n0 + wx * 64 + j * 16 + (lane & 15);
            if (nn < N) {
                #pragma unroll
                for (int r = 0; r < 4; r++) {
                    const size_t idx = (size_t)(mb + r) * N + nn;
                    float v = acc[i][j][r];
                    if (EPI == 1) v += resid_f[idx];
                    Cf[idx] = v;
                }
            }
        }
    }
}

// ---- depthwise causal conv (k=4) + bias + silu over xBC channels ----
__global__ __launch_bounds__(256) void conv_silu_kernel(
    const float* __restrict__ zx, const float* __restrict__ cw,
    const float* __restrict__ cb, float* __restrict__ out)
{
    const int idx = blockIdx.x * 256 + threadIdx.x;
    if (idx >= NTOK * CONVDIM) return;
    const int c = idx % CONVDIM;
    const int token = idx / CONVDIM;
    const int l = token & (SEQLEN - 1);
    float acc = cb[c];
    #pragma unroll
    for (int k = 0; k < 4; k++) {
        const int ls = l - 3 + k;
        if (ls >= 0)
            acc += zx[(size_t)(token - 3 + k) * DINPROJ + DINNER + c] * cw[c * 4 + k];
    }
    out[(size_t)token * CONVDIM + c] = acc / (1.f + expf(-acc));   // silu
}

// ---- dt = softplus(dt_raw + dt_bias) ----
__global__ __launch_bounds__(256) void dt_softplus_kernel(
    const float* __restrict__ zx, const float* __restrict__ dtb,
    float* __restrict__ out)
{
    const int idx = blockIdx.x * 256 + threadIdx.x;   // NTOK*NHEADS
    const int h = idx & (NHEADS - 1);
    const int token = idx >> 5;
    float v = zx[(size_t)token * DINPROJ + (DINNER + CONVDIM) + h] + dtb[h];
    out[idx] = (v > 20.f) ? v : log1pf(expf(v));
}

// ================= chunked scan =================
// Phase A: per-chunk state S_c[p,n] = sum_l exp(cumQ-cum[l]) dt_l x[l,p] B[l,n]
// grid: 1024 = bh*16 + c
__global__ __launch_bounds__(256) void chunk_state_kernel(
    const float* __restrict__ convb, const float* __restrict__ dtb,
    const float* __restrict__ A_log, float* __restrict__ ccum,
    ushort_t* __restrict__ Sbuf)
{
    const int bx = blockIdx.x;
    const int bh = bx >> 4, c = bx & 15;
    const int b = bh >> 5, h = bh & 31;
    const int t = threadIdx.x;
    const int p = t >> 2, q = t & 3;
    const int tok0 = b * SEQLEN + c * Q;
    const float A = -expf(A_log[h]);

    __shared__ float sX[Q * 66];
    __shared__ float sB[Q * 132];
    __shared__ float sW[Q];

    for (int i = t; i < Q * HEADDIM; i += 256) {
        const int row = i >> 6, col = i & 63;
        sX[row * 66 + col] = convb[(size_t)(tok0 + row) * CONVDIM + h * HEADDIM + col];
    }
    for (int i = t; i < Q * DSTATE; i += 256) {
        const int row = i >> 7, col = i & 127;
        sB[row * 132 + col] = convb[(size_t)(tok0 + row) * CONVDIM + DINNER + col];
    }
    if (t < Q) {
        const float d = dtb[(size_t)(tok0 + t) * NHEADS + h];
        float s = d;
        #pragma unroll
        for (int off = 1; off < 64; off <<= 1) {
            const float up = __shfl_up(s, off);
            if (t >= off) s += up;
        }
        const float total = __shfl(s, 63);
        sW[t] = expf(A * (total - s)) * d;     // arg <= 0
        if (t == 63) ccum[bh * NCHUNK + c] = A * total;
    }
    __syncthreads();

    float acc[32] = {};
    for (int l = 0; l < Q; l++) {
        const float wx = sW[l] * sX[l * 66 + p];
        #pragma unroll
        for (int jj = 0; jj < 8; jj++) {
            const f32x4 bv = *(const f32x4*)&sB[l * 132 + q * 4 + 16 * jj];
            #pragma unroll
            for (int k = 0; k < 4; k++)
                acc[jj * 4 + k] += wx * bv[k];
        }
    }
    const size_t slot = ((size_t)(bh * NCHUNK + c) * 64 + p) * 128;
    #pragma unroll
    for (int jj = 0; jj < 8; jj++) {
        u16x4 sv;
        #pragma unroll
        for (int k = 0; k < 4; k++) sv[k] = f2bfu(acc[jj * 4 + k]);
        *(u16x4*)&Sbuf[slot + q * 4 + 16 * jj] = sv;
    }
}

// Phase B: sequential stitch over chunks; writes incoming H_c into slot c.
// grid: 64 = bh
__global__ __launch_bounds__(256) void stitch_kernel(
    const float* __restrict__ ccum, ushort_t* __restrict__ Sbuf)
{
    const int bh = blockIdx.x;
    const int t = threadIdx.x, p = t >> 2, q = t & 3;
    float H[32];
    #pragma unroll
    for (int j = 0; j < 32; j++) H[j] = 0.f;
    for (int c = 0; c < NCHUNK; c++) {
        const float P = expf(ccum[bh * NCHUNK + c]);
        const size_t slot = ((size_t)(bh * NCHUNK + c) * 64 + p) * 128;
        #pragma unroll
        for (int jj = 0; jj < 8; jj++) {
            const u16x4 sv4 = *(const u16x4*)&Sbuf[slot + q * 4 + 16 * jj];
            u16x4 hv4;
            #pragma unroll
            for (int k = 0; k < 4; k++) hv4[k] = f2bfu(H[jj * 4 + k]);
            *(u16x4*)&Sbuf[slot + q * 4 + 16 * jj] = hv4;
            #pragma unroll
            for (int k = 0; k < 4; k++)
                H[jj * 4 + k] = P * H[jj * 4 + k] + bfu2f(sv4[k]);
        }
    }
}

// Phase C: per-chunk sequential recurrence from H_c, all inputs in LDS.
// grid: 1024 = bh*16 + c
__global__ __launch_bounds__(256) void chunk_scan_kernel(
    const float* __restrict__ convb, const float* __restrict__ dtb,
    const float* __restrict__ A_log, const float* __restrict__ Dh,
    const ushort_t* __restrict__ Sbuf, bf16* __restrict__ ybuf)
{
    const int bx = blockIdx.x;
    const int bh = bx >> 4, c = bx & 15;
    const int b = bh >> 5, h = bh & 31;
    const int t = threadIdx.x;
    const int p = t >> 2, q = t & 3;
    const int tok0 = b * SEQLEN + c * Q;
    const float A = -expf(A_log[h]);
    const float Dv = Dh[h];

    __shared__ ushort_t sB[Q * 136];
    __shared__ ushort_t sC[Q * 136];
    __shared__ ushort_t sX[Q * 68];
    __shared__ float    sY[Q * 66];
    __shared__ float    sDt[Q];

    // stage X (bf16 pairs)
    for (int i = t; i < Q * 32; i += 256) {
        const int row = i >> 5, col = (i & 31) * 2;
        const float* src = &convb[(size_t)(tok0 + row) * CONVDIM + h * HEADDIM + col];
        *(unsigned*)&sX[row * 68 + col] = packbf2(src[0], src[1]);
    }
    // stage B, C (bf16 pairs)
    for (int i = t; i < Q * 64; i += 256) {
        const int row = i >> 6, col = (i & 63) * 2;
        const float* srcB = &convb[(size_t)(tok0 + row) * CONVDIM + DINNER + col];
        *(unsigned*)&sB[row * 136 + col] = packbf2(srcB[0], srcB[1]);
        const float* srcC = &convb[(size_t)(tok0 + row) * CONVDIM + DINNER + DSTATE + col];
        *(unsigned*)&sC[row * 136 + col] = packbf2(srcC[0], srcC[1]);
    }
    if (t < Q) sDt[t] = dtb[(size_t)(tok0 + t) * NHEADS + h];

    // load incoming state H_c (bf16) into registers
    float hs[32];
    const size_t slot = ((size_t)(bh * NCHUNK + c) * 64 + p) * 128;
    #pragma unroll
    for (int jj = 0; jj < 8; jj++) {
        const u16x4 hv4 = *(const u16x4*)&Sbuf[slot + q * 4 + 16 * jj];
        #pragma unroll
        for (int k = 0; k < 4; k++) hs[jj * 4 + k] = bfu2f(hv4[k]);
    }
    __syncthreads();

    for (int l = 0; l < Q; l++) {
        const float dt_l = sDt[l];
        const float dA = expf(dt_l * A);
        const float xp = bfu2f(sX[l * 68 + p]);
        const float coef = dt_l * xp;
        float ysum = 0.f;
        #pragma unroll
        for (int jj = 0; jj < 8; jj++) {
            const u16x4 bv = *(const u16x4*)&sB[l * 136 + q * 4 + 16 * jj];
            const u16x4 cv = *(const u16x4*)&sC[l * 136 + q * 4 + 16 * jj];
            #pragma unroll
            for (int k = 0; k < 4; k++) {
                const float hv = hs[jj * 4 + k] * dA + coef * bfu2f(bv[k]);
                hs[jj * 4 + k] = hv;
                ysum += hv * bfu2f(cv[k]);
            }
        }
        ysum += __shfl_xor(ysum, 1);
        ysum += __shfl_xor(ysum, 2);
        if (q == 0) sY[l * 66 + p] = ysum + Dv * xp;
    }
    __syncthreads();
    for (int i = t; i < Q * 64; i += 256) {
        const int row = i >> 6, col = i & 63;
        ybuf[(size_t)(tok0 + row) * DINNER + h * HEADDIM + col] =
            __float2bfloat16(sY[row * 66 + col]);
    }
}

// ---- ynorm = rmsnorm(y * silu(z)) over 2048 dims -> bf16 (y is bf16) ----
__global__ __launch_bounds__(256) void gated_rmsnorm_kernel(
    const bf16* __restrict__ y, const float* __restrict__ zx,
    const float* __restrict__ w, bf16* __restrict__ out)
{
    const int token = blockIdx.x, t = threadIdx.x;
    const bf16* yr = y + (size_t)token * DINNER;
    const float* zr = zx + (size_t)token * DINPROJ;   // z = first 2048
    float v[8]; float ss = 0.f;
    #pragma unroll
    for (int i = 0; i < 8; i++) {
        const int idx = t * 8 + i;
        const float zz = zr[idx];
        const float val = bf2f(yr[idx]) * (zz / (1.f + expf(-zz)));
        v[i] = val; ss += val * val;
    }
    ss = block_reduce_sum(ss);
    const float scale = rsqrtf(ss * (1.0f / DINNER) + 1e-6f);
    #pragma unroll
    for (int i = 0; i < 8; i++) {
        const int idx = t * 8 + i;
        out[(size_t)token * DINNER + idx] =
            __float2bfloat16(v[i] * scale * w[idx]);
    }
}

// ---- act = bf16(silu(g) * u) ----
__global__ __launch_bounds__(256) void silu_mul_kernel(
    const float* __restrict__ g, const float* __restrict__ u,
    bf16* __restrict__ act, int n)
{
    const int i = blockIdx.x * 256 + threadIdx.x;
    if (i < n) {
        const float gv = g[i];
        act[i] = __float2bfloat16((gv / (1.f + expf(-gv))) * u[i]);
    }
}

extern "C" void kernel_launch(void* const* d_in, const int* in_sizes, int n_in,
                              void* d_out, int out_size, void* d_ws, size_t ws_size,
                              hipStream_t stream) {
    const float* hidden     = (const float*)d_in[0];
    const float* norm_w     = (const float*)d_in[1];
    const float* in_proj_w  = (const float*)d_in[2];
    const float* conv_w     = (const float*)d_in[3];
    const float* conv_b     = (const float*)d_in[4];
    const float* dt_bias    = (const float*)d_in[5];
    const float* A_log      = (const float*)d_in[6];
    const float* Dh         = (const float*)d_in[7];
    const float* ssm_norm_w = (const float*)d_in[8];
    const float* out_proj_w = (const float*)d_in[9];
    const float* post_norm_w= (const float*)d_in[10];
    const float* gate_w     = (const float*)d_in[11];
    const float* up_w       = (const float*)d_in[12];
    const float* down_w     = (const float*)d_in[13];
    float* out = (float*)d_out;

    // ---- workspace layout (float slots; peak = 22,152,192 fl = 88.6 MB) ----
    float* ws = (float*)d_ws;
    bf16*  h_norm = (bf16*)(ws);               // [0, 1,048,576)
    float* zx     = ws + 1048576;              // [1,048,576, 10,027,008)
    bf16*  ybuf   = (bf16*)(ws + 10027008);    // [10,027,008, 11,075,584) bf16 2048x2048
    float* convb  = ws + 11075584;             // [11,075,584, 15,794,176)
    float* dtb    = ws + 15794176;             // [15,794,176, 15,859,712)
    float* ccum   = ws + 15859712;             // [15,859,712, 15,860,736)
    ushort_t* Sbuf= (ushort_t*)(ws + 15860736);// [15,860,736, 20,055,040) bf16 64*16*64*128
    float* xbuf   = ws + 20055040;             // [20,055,040, 22,152,192)
    bf16*  ynorm  = (bf16*)(ws + 11075584);    // reuse convb (dead after phase C)
    bf16*  h2     = h_norm;                    // reuse (dead after in_proj)
    float* gbuf   = ws + 1048576;              // reuse zx (z dead after step 6)
    float* ubuf   = ws + 11075584;             // reuse convb..Sbuf-head (dead)
    bf16*  act    = (bf16*)(ws + 16711680);    // reuse Sbuf tail (dead after C)

    // 1. h = rmsnorm(hidden, norm_w)  -> bf16
    rmsnorm1024_kernel<<<NTOK, 256, 0, stream>>>(hidden, norm_w, h_norm);
    // 2. zxbcdt = h @ in_proj_w^T   (f32 out)
    gemm_mfma<0><<<dim3(35, 16), 256, 0, stream>>>(h_norm, in_proj_w, zx,
        nullptr, NTOK, DINPROJ, DMODEL);
    // 3. conv(k=4) + bias + silu on xBC
    conv_silu_kernel<<<(NTOK * CONVDIM) / 256, 256, 0, stream>>>(zx, conv_w, conv_b, convb);
    // 4. dt = softplus(dt_raw + dt_bias)
    dt_softplus_kernel<<<(NTOK * NHEADS) / 256, 256, 0, stream>>>(zx, dt_bias, dtb);
    // 5. chunked selective scan -> ybuf (bf16)
    chunk_state_kernel<<<1024, 256, 0, stream>>>(convb, dtb, A_log, ccum, Sbuf);
    stitch_kernel<<<64, 256, 0, stream>>>(ccum, Sbuf);
    chunk_scan_kernel<<<1024, 256, 0, stream>>>(convb, dtb, A_log, Dh, Sbuf, ybuf);
    // 6. ynorm = rmsnorm(y * silu(z), ssm_norm_w)  -> bf16
    gated_rmsnorm_kernel<<<NTOK, 256, 0, stream>>>(ybuf, zx, ssm_norm_w, ynorm);
    // 7. x = hidden + ynorm @ out_proj_w^T  (f32)
    gemm_mfma<1><<<dim3(8, 16), 256, 0, stream>>>(ynorm, out_proj_w, xbuf,
        hidden, NTOK, DMODEL, DINNER);
    // 8. h2 = rmsnorm(x, post_norm_w)  -> bf16
    rmsnorm1024_kernel<<<NTOK, 256, 0, stream>>>(xbuf, post_norm_w, h2);
    // 9. g = h2 @ gate_w^T ; u = h2 @ up_w^T  (f32)
    gemm_mfma<0><<<dim3(22, 16), 256, 0, stream>>>(h2, gate_w, gbuf,
        nullptr, NTOK, INTER, DMODEL);
    gemm_mfma<0><<<dim3(22, 16), 256, 0, stream>>>(h2, up_w, ubuf,
        nullptr, NTOK, INTER, DMODEL);
    // 10. act = bf16(silu(g) * u)
    silu_mul_kernel<<<(NTOK * INTER) / 256, 256, 0, stream>>>(gbuf, ubuf, act, NTOK * INTER);
    // 11. out = x + act @ down_w^T   (f32 to d_out)
    gemm_mfma<1><<<dim3(8, 16), 256, 0, stream>>>(act, down_w, out,
        xbuf, NTOK, DMODEL, INTER);
}

// Round 8
// 532.997 us; speedup vs baseline: 5.3608x; 1.1482x over previous
//
#include <hip/hip_runtime.h>
#include <hip/hip_bf16.h>

// ---- problem constants ----
#define SEQLEN   1024
#define NTOK     2048          // BATCH * SEQLEN
#define DMODEL   1024
#define DSTATE   128
#define DINNER   2048
#define NHEADS   32
#define HEADDIM  64
#define CONVDIM  2304          // DINNER + 2*DSTATE
#define DINPROJ  4384          // 2*DINNER + 2*DSTATE + NHEADS
#define INTER    2752
#define Q        64            // scan chunk length
#define NCHUNK   16            // SEQLEN / Q

typedef __hip_bfloat16 bf16;
typedef unsigned short ushort_t;
typedef __attribute__((ext_vector_type(8))) short bf16x8;
typedef __attribute__((ext_vector_type(4))) float f32x4;
typedef __attribute__((ext_vector_type(4))) unsigned short u16x4;

__device__ __forceinline__ float bf2f(bf16 x) { return __bfloat162float(x); }
__device__ __forceinline__ float bfu2f(ushort_t u) {
    return __uint_as_float(((unsigned)u) << 16);
}
__device__ __forceinline__ ushort_t f2bfu(float x) {
    union { bf16 h; ushort_t u; } c; c.h = __float2bfloat16(x); return c.u;
}
__device__ __forceinline__ unsigned packbf2(float x, float y) {
    return ((unsigned)f2bfu(y) << 16) | f2bfu(x);
}

__device__ __forceinline__ void glds16(const void* g, void* l) {
    __builtin_amdgcn_global_load_lds(
        (const __attribute__((address_space(1))) void*)g,
        (__attribute__((address_space(3))) void*)l, 16, 0, 0);
}

__device__ inline float block_reduce_sum(float v) {
    __shared__ float red[4];
    #pragma unroll
    for (int off = 32; off >= 1; off >>= 1) v += __shfl_down(v, off);
    int lane = threadIdx.x & 63, w = threadIdx.x >> 6;
    if (lane == 0) red[w] = v;
    __syncthreads();
    return red[0] + red[1] + red[2] + red[3];
}

// ---- fp32 -> bf16 weight convert (4 elems/thread) ----
__global__ __launch_bounds__(256) void f2bf_kernel(
    const float* __restrict__ src, ushort_t* __restrict__ dst, int n)
{
    const int i = (blockIdx.x * 256 + threadIdx.x) * 4;
    if (i < n) {
        const f32x4 v = *(const f32x4*)(src + i);
        u16x4 o;
        #pragma unroll
        for (int k = 0; k < 4; k++) o[k] = f2bfu(v[k]);
        *(u16x4*)(dst + i) = o;
    }
}

// ---- RMSNorm over 1024 dims (fp32 in, fp32 weights) -> bf16 out ----
__global__ __launch_bounds__(256) void rmsnorm1024_kernel(
    const float* __restrict__ x, const float* __restrict__ w, bf16* __restrict__ out)
{
    const int token = blockIdx.x, t = threadIdx.x;
    float v[4]; float ss = 0.f;
    #pragma unroll
    for (int i = 0; i < 4; i++) {
        v[i] = x[(size_t)token * DMODEL + t * 4 + i];
        ss += v[i] * v[i];
    }
    ss = block_reduce_sum(ss);
    const float scale = rsqrtf(ss * (1.0f / DMODEL) + 1e-6f);
    #pragma unroll
    for (int i = 0; i < 4; i++)
        out[(size_t)token * DMODEL + t * 4 + i] =
            __float2bfloat16(v[i] * scale * w[t * 4 + i]);
}

// ---- MFMA GEMM (async staging): C(MxN f32) = A(MxK bf16) @ W(NxK bf16)^T ----
// 128x128 tile, BK=32, 256 thr (4 waves 2x2), global_load_lds width=16
// EPI 0: Cf=acc ; EPI 1: Cf=acc+resid_f
template <int EPI>
__global__ __launch_bounds__(256) void gemm_bf(
    const bf16* __restrict__ A, const bf16* __restrict__ W,
    float* __restrict__ Cf, const float* __restrict__ resid_f,
    int M, int N, int K)
{
    __shared__ ushort_t As[128 * 32];
    __shared__ ushort_t Bs[128 * 32];
    const int tid = threadIdx.x;
    const int w = tid >> 6, lane = tid & 63;
    const int m0 = blockIdx.y * 128, n0 = blockIdx.x * 128;

    // staging: transfer covers rows srow(+64), k-chunk skof..skof+8
    const int srow = tid >> 2;
    const int skof = (tid & 3) * 8;
    const bf16* Ag0 = A + (size_t)(m0 + srow) * K + skof;
    const bf16* Ag1 = Ag0 + (size_t)64 * K;
    const int nr0 = n0 + srow, nr1 = n0 + 64 + srow;
    const bf16* Wg0 = W + (size_t)(nr0 < N ? nr0 : 0) * K + skof;   // clamp OOB row
    const bf16* Wg1 = W + (size_t)(nr1 < N ? nr1 : 0) * K + skof;
    ushort_t* lA0 = &As[w * 512];          // wave-uniform LDS bases
    ushort_t* lA1 = &As[2048 + w * 512];
    ushort_t* lB0 = &Bs[w * 512];
    ushort_t* lB1 = &Bs[2048 + w * 512];

    const int wy = w >> 1, wx = w & 1;
    const int fr = lane & 15;
    const int fk = (lane >> 4) * 8;
    f32x4 acc[4][4];
    #pragma unroll
    for (int i = 0; i < 4; i++)
        #pragma unroll
        for (int j = 0; j < 4; j++)
            acc[i][j] = (f32x4){0.f, 0.f, 0.f, 0.f};

    for (int k0 = 0; k0 < K; k0 += 32) {
        __syncthreads();                   // prev iter's LDS reads done
        glds16(Ag0 + k0, lA0);
        glds16(Ag1 + k0, lA1);
        glds16(Wg0 + k0, lB0);
        glds16(Wg1 + k0, lB1);
        __syncthreads();                   // drains vmcnt -> LDS ready
        bf16x8 af[4], bfv[4];
        #pragma unroll
        for (int i = 0; i < 4; i++)
            af[i] = *(const bf16x8*)&As[(wy * 64 + i * 16 + fr) * 32 + fk];
        #pragma unroll
        for (int j = 0; j < 4; j++)
            bfv[j] = *(const bf16x8*)&Bs[(wx * 64 + j * 16 + fr) * 32 + fk];
        #pragma unroll
        for (int i = 0; i < 4; i++)
            #pragma unroll
            for (int j = 0; j < 4; j++)
                acc[i][j] = __builtin_amdgcn_mfma_f32_16x16x32_bf16(
                    af[i], bfv[j], acc[i][j], 0, 0, 0);
    }

    // C/D layout: col = lane&15, row = (lane>>4)*4 + reg
    #pragma unroll
    for (int i = 0; i < 4; i++) {
        #pragma unroll
        for (int j = 0; j < 4; j++) {
            const int mb = m0 + wy * 64 + i * 16 + (lane >> 4) * 4;
            const int nn = n0 + wx * 64 + j * 16 + (lane & 15);
            if (nn < N) {
                #pragma unroll
                for (int r = 0; r < 4; r++) {
                    const size_t idx = (size_t)(mb + r) * N + nn;
                    float v = acc[i][j][r];
                    if (EPI == 1) v += resid_f[idx];
                    Cf[idx] = v;
                }
            }
        }
    }
}

// ---- depthwise causal conv (k=4) + bias + silu over xBC channels ----
__global__ __launch_bounds__(256) void conv_silu_kernel(
    const float* __restrict__ zx, const float* __restrict__ cw,
    const float* __restrict__ cb, float* __restrict__ out)
{
    const int idx = blockIdx.x * 256 + threadIdx.x;
    if (idx >= NTOK * CONVDIM) return;
    const int c = idx % CONVDIM;
    const int token = idx / CONVDIM;
    const int l = token & (SEQLEN - 1);
    float acc = cb[c];
    #pragma unroll
    for (int k = 0; k < 4; k++) {
        const int ls = l - 3 + k;
        if (ls >= 0)
            acc += zx[(size_t)(token - 3 + k) * DINPROJ + DINNER + c] * cw[c * 4 + k];
    }
    out[(size_t)token * CONVDIM + c] = acc / (1.f + expf(-acc));   // silu
}

// ---- dt = softplus(dt_raw + dt_bias) ----
__global__ __launch_bounds__(256) void dt_softplus_kernel(
    const float* __restrict__ zx, const float* __restrict__ dtb,
    float* __restrict__ out)
{
    const int idx = blockIdx.x * 256 + threadIdx.x;   // NTOK*NHEADS
    const int h = idx & (NHEADS - 1);
    const int token = idx >> 5;
    float v = zx[(size_t)token * DINPROJ + (DINNER + CONVDIM) + h] + dtb[h];
    out[idx] = (v > 20.f) ? v : log1pf(expf(v));
}

// ================= chunked scan =================
// Phase A: per-chunk state S_c[p,n] = sum_l exp(cumQ-cum[l]) dt_l x[l,p] B[l,n]
__global__ __launch_bounds__(256) void chunk_state_kernel(
    const float* __restrict__ convb, const float* __restrict__ dtb,
    const float* __restrict__ A_log, float* __restrict__ ccum,
    ushort_t* __restrict__ Sbuf)
{
    const int bx = blockIdx.x;
    const int bh = bx >> 4, c = bx & 15;
    const int b = bh >> 5, h = bh & 31;
    const int t = threadIdx.x;
    const int p = t >> 2, q = t & 3;
    const int tok0 = b * SEQLEN + c * Q;
    const float A = -expf(A_log[h]);

    __shared__ float sX[Q * 66];
    __shared__ float sB[Q * 132];
    __shared__ float sW[Q];

    for (int i = t; i < Q * HEADDIM; i += 256) {
        const int row = i >> 6, col = i & 63;
        sX[row * 66 + col] = convb[(size_t)(tok0 + row) * CONVDIM + h * HEADDIM + col];
    }
    for (int i = t; i < Q * DSTATE; i += 256) {
        const int row = i >> 7, col = i & 127;
        sB[row * 132 + col] = convb[(size_t)(tok0 + row) * CONVDIM + DINNER + col];
    }
    if (t < Q) {
        const float d = dtb[(size_t)(tok0 + t) * NHEADS + h];
        float s = d;
        #pragma unroll
        for (int off = 1; off < 64; off <<= 1) {
            const float up = __shfl_up(s, off);
            if (t >= off) s += up;
        }
        const float total = __shfl(s, 63);
        sW[t] = expf(A * (total - s)) * d;     // arg <= 0
        if (t == 63) ccum[bh * NCHUNK + c] = A * total;
    }
    __syncthreads();

    float acc[32] = {};
    for (int l = 0; l < Q; l++) {
        const float wx = sW[l] * sX[l * 66 + p];
        #pragma unroll
        for (int jj = 0; jj < 8; jj++) {
            const f32x4 bv = *(const f32x4*)&sB[l * 132 + q * 4 + 16 * jj];
            #pragma unroll
            for (int k = 0; k < 4; k++)
                acc[jj * 4 + k] += wx * bv[k];
        }
    }
    const size_t slot = ((size_t)(bh * NCHUNK + c) * 64 + p) * 128;
    #pragma unroll
    for (int jj = 0; jj < 8; jj++) {
        u16x4 sv;
        #pragma unroll
        for (int k = 0; k < 4; k++) sv[k] = f2bfu(acc[jj * 4 + k]);
        *(u16x4*)&Sbuf[slot + q * 4 + 16 * jj] = sv;
    }
}

// Phase B: sequential stitch; writes incoming H_c into slot c.
__global__ __launch_bounds__(256) void stitch_kernel(
    const float* __restrict__ ccum, ushort_t* __restrict__ Sbuf)
{
    const int bh = blockIdx.x;
    const int t = threadIdx.x, p = t >> 2, q = t & 3;
    float H[32];
    #pragma unroll
    for (int j = 0; j < 32; j++) H[j] = 0.f;
    for (int c = 0; c < NCHUNK; c++) {
        const float P = expf(ccum[bh * NCHUNK + c]);
        const size_t slot = ((size_t)(bh * NCHUNK + c) * 64 + p) * 128;
        #pragma unroll
        for (int jj = 0; jj < 8; jj++) {
            const u16x4 sv4 = *(const u16x4*)&Sbuf[slot + q * 4 + 16 * jj];
            u16x4 hv4;
            #pragma unroll
            for (int k = 0; k < 4; k++) hv4[k] = f2bfu(H[jj * 4 + k]);
            *(u16x4*)&Sbuf[slot + q * 4 + 16 * jj] = hv4;
            #pragma unroll
            for (int k = 0; k < 4; k++)
                H[jj * 4 + k] = P * H[jj * 4 + k] + bfu2f(sv4[k]);
        }
    }
}

// Phase C: per-chunk sequential recurrence from H_c, all inputs in LDS.
__global__ __launch_bounds__(256) void chunk_scan_kernel(
    const float* __restrict__ convb, const float* __restrict__ dtb,
    const float* __restrict__ A_log, const float* __restrict__ Dh,
    const ushort_t* __restrict__ Sbuf, bf16* __restrict__ ybuf)
{
    const int bx = blockIdx.x;
    const int bh = bx >> 4, c = bx & 15;
    const int b = bh >> 5, h = bh & 31;
    const int t = threadIdx.x;
    const int p = t >> 2, q = t & 3;
    const int tok0 = b * SEQLEN + c * Q;
    const float A = -expf(A_log[h]);
    const float Dv = Dh[h];

    __shared__ ushort_t sB[Q * 136];
    __shared__ ushort_t sC[Q * 136];
    __shared__ ushort_t sX[Q * 68];
    __shared__ float    sY[Q * 66];
    __shared__ float    sDt[Q];

    for (int i = t; i < Q * 32; i += 256) {
        const int row = i >> 5, col = (i & 31) * 2;
        const float* src = &convb[(size_t)(tok0 + row) * CONVDIM + h * HEADDIM + col];
        *(unsigned*)&sX[row * 68 + col] = packbf2(src[0], src[1]);
    }
    for (int i = t; i < Q * 64; i += 256) {
        const int row = i >> 6, col = (i & 63) * 2;
        const float* srcB = &convb[(size_t)(tok0 + row) * CONVDIM + DINNER + col];
        *(unsigned*)&sB[row * 136 + col] = packbf2(srcB[0], srcB[1]);
        const float* srcC = &convb[(size_t)(tok0 + row) * CONVDIM + DINNER + DSTATE + col];
        *(unsigned*)&sC[row * 136 + col] = packbf2(srcC[0], srcC[1]);
    }
    if (t < Q) sDt[t] = dtb[(size_t)(tok0 + t) * NHEADS + h];

    float hs[32];
    const size_t slot = ((size_t)(bh * NCHUNK + c) * 64 + p) * 128;
    #pragma unroll
    for (int jj = 0; jj < 8; jj++) {
        const u16x4 hv4 = *(const u16x4*)&Sbuf[slot + q * 4 + 16 * jj];
        #pragma unroll
        for (int k = 0; k < 4; k++) hs[jj * 4 + k] = bfu2f(hv4[k]);
    }
    __syncthreads();

    for (int l = 0; l < Q; l++) {
        const float dt_l = sDt[l];
        const float dA = expf(dt_l * A);
        const float xp = bfu2f(sX[l * 68 + p]);
        const float coef = dt_l * xp;
        float ysum = 0.f;
        #pragma unroll
        for (int jj = 0; jj < 8; jj++) {
            const u16x4 bv = *(const u16x4*)&sB[l * 136 + q * 4 + 16 * jj];
            const u16x4 cv = *(const u16x4*)&sC[l * 136 + q * 4 + 16 * jj];
            #pragma unroll
            for (int k = 0; k < 4; k++) {
                const float hv = hs[jj * 4 + k] * dA + coef * bfu2f(bv[k]);
                hs[jj * 4 + k] = hv;
                ysum += hv * bfu2f(cv[k]);
            }
        }
        ysum += __shfl_xor(ysum, 1);
        ysum += __shfl_xor(ysum, 2);
        if (q == 0) sY[l * 66 + p] = ysum + Dv * xp;
    }
    __syncthreads();
    for (int i = t; i < Q * 64; i += 256) {
        const int row = i >> 6, col = i & 63;
        ybuf[(size_t)(tok0 + row) * DINNER + h * HEADDIM + col] =
            __float2bfloat16(sY[row * 66 + col]);
    }
}

// ---- ynorm = rmsnorm(y * silu(z)) over 2048 dims -> bf16 (y is bf16) ----
__global__ __launch_bounds__(256) void gated_rmsnorm_kernel(
    const bf16* __restrict__ y, const float* __restrict__ zx,
    const float* __restrict__ w, bf16* __restrict__ out)
{
    const int token = blockIdx.x, t = threadIdx.x;
    const bf16* yr = y + (size_t)token * DINNER;
    const float* zr = zx + (size_t)token * DINPROJ;   // z = first 2048
    float v[8]; float ss = 0.f;
    #pragma unroll
    for (int i = 0; i < 8; i++) {
        const int idx = t * 8 + i;
        const float zz = zr[idx];
        const float val = bf2f(yr[idx]) * (zz / (1.f + expf(-zz)));
        v[i] = val; ss += val * val;
    }
    ss = block_reduce_sum(ss);
    const float scale = rsqrtf(ss * (1.0f / DINNER) + 1e-6f);
    #pragma unroll
    for (int i = 0; i < 8; i++) {
        const int idx = t * 8 + i;
        out[(size_t)token * DINNER + idx] =
            __float2bfloat16(v[i] * scale * w[idx]);
    }
}

// ---- act = bf16(silu(g) * u) from combined gu (2048 x 5504) ----
__global__ __launch_bounds__(256) void silu_mul_kernel(
    const float* __restrict__ gu, bf16* __restrict__ act, int n)
{
    const int i = blockIdx.x * 256 + threadIdx.x;
    if (i < n) {
        const int m = i / INTER, j = i - m * INTER;
        const float g = gu[(size_t)m * (2 * INTER) + j];
        const float u = gu[(size_t)m * (2 * INTER) + INTER + j];
        act[i] = __float2bfloat16((g / (1.f + expf(-g))) * u);
    }
}

extern "C" void kernel_launch(void* const* d_in, const int* in_sizes, int n_in,
                              void* d_out, int out_size, void* d_ws, size_t ws_size,
                              hipStream_t stream) {
    const float* hidden     = (const float*)d_in[0];
    const float* norm_w     = (const float*)d_in[1];
    const float* in_proj_w  = (const float*)d_in[2];
    const float* conv_w     = (const float*)d_in[3];
    const float* conv_b     = (const float*)d_in[4];
    const float* dt_bias    = (const float*)d_in[5];
    const float* A_log      = (const float*)d_in[6];
    const float* Dh         = (const float*)d_in[7];
    const float* ssm_norm_w = (const float*)d_in[8];
    const float* out_proj_w = (const float*)d_in[9];
    const float* post_norm_w= (const float*)d_in[10];
    const float* gate_w     = (const float*)d_in[11];
    const float* up_w       = (const float*)d_in[12];
    const float* down_w     = (const float*)d_in[13];
    float* out = (float*)d_out;

    // ---- workspace layout (fl units; peak = 23,200,768 fl = 92.8 MB) ----
    float* ws = (float*)d_ws;
    bf16*  h_norm = (bf16*)(ws);                 // [0, 1,048,576)
    float* zx     = ws + 1048576;                // [1,048,576, 10,027,008)
    float* convb  = ws + 10027008;               // [10,027,008, 14,745,600)
    float* dtb    = ws + 14745600;               // [14,745,600, 14,811,136)
    float* ccum   = ws + 14811136;               // 1024 fl
    ushort_t* Sbuf= (ushort_t*)(ws + 14812160);  // [14,812,160, 19,006,464) bf16
    float* xbuf   = ws + 19006464;               // [19,006,464, 21,103,616)
    bf16*  ybuf   = (bf16*)(ws + 21103616);      // [21,103,616, 22,152,192)
    bf16*  ynorm  = (bf16*)(ws + 22152192);      // [22,152,192, 23,200,768)
    // just-in-time bf16 weights in dead regions:
    ushort_t* Wip = (ushort_t*)(ws + 10027008);  // convb region, dead before conv
    ushort_t* Wop = (ushort_t*)(ws + 1048576);   // zx region, after z consumed
    ushort_t* Wgu = (ushort_t*)(ws + 2097152);   // gate rows 0..2751, up 2752..5503
    ushort_t* Wdn = (ushort_t*)(ws + 4915200);
    float* gu     = ws + 6324224;                // [6,324,224, 17,596,416) f32 2048x5504
    bf16*  h2     = h_norm;                      // reuse
    bf16*  act    = (bf16*)(ws + 1048576);       // over Wop/Wgu-head (dead by then)

    // 0a. Wip = bf16(in_proj_w)
    f2bf_kernel<<<4384, 256, 0, stream>>>(in_proj_w, Wip, DINPROJ * DMODEL);
    // 1. h = rmsnorm(hidden, norm_w)  -> bf16
    rmsnorm1024_kernel<<<NTOK, 256, 0, stream>>>(hidden, norm_w, h_norm);
    // 2. zxbcdt = h @ Wip^T   (f32 out)
    gemm_bf<0><<<dim3(35, 16), 256, 0, stream>>>(h_norm, (const bf16*)Wip, zx,
        nullptr, NTOK, DINPROJ, DMODEL);
    // 3. conv(k=4) + bias + silu on xBC
    conv_silu_kernel<<<(NTOK * CONVDIM) / 256, 256, 0, stream>>>(zx, conv_w, conv_b, convb);
    // 4. dt = softplus(dt_raw + dt_bias)
    dt_softplus_kernel<<<(NTOK * NHEADS) / 256, 256, 0, stream>>>(zx, dt_bias, dtb);
    // 5. chunked selective scan -> ybuf (bf16)
    chunk_state_kernel<<<1024, 256, 0, stream>>>(convb, dtb, A_log, ccum, Sbuf);
    stitch_kernel<<<64, 256, 0, stream>>>(ccum, Sbuf);
    chunk_scan_kernel<<<1024, 256, 0, stream>>>(convb, dtb, A_log, Dh, Sbuf, ybuf);
    // 6. ynorm = rmsnorm(y * silu(z), ssm_norm_w)  -> bf16 (last use of zx)
    gated_rmsnorm_kernel<<<NTOK, 256, 0, stream>>>(ybuf, zx, ssm_norm_w, ynorm);
    // 6b. convert remaining weights into dead zx region
    f2bf_kernel<<<2048, 256, 0, stream>>>(out_proj_w, Wop, DMODEL * DINNER);
    f2bf_kernel<<<2752, 256, 0, stream>>>(gate_w, Wgu, INTER * DMODEL);
    f2bf_kernel<<<2752, 256, 0, stream>>>(up_w, Wgu + INTER * DMODEL, INTER * DMODEL);
    f2bf_kernel<<<2752, 256, 0, stream>>>(down_w, Wdn, DMODEL * INTER);
    // 7. x = hidden + ynorm @ Wop^T  (f32)
    gemm_bf<1><<<dim3(8, 16), 256, 0, stream>>>(ynorm, (const bf16*)Wop, xbuf,
        hidden, NTOK, DMODEL, DINNER);
    // 8. h2 = rmsnorm(x, post_norm_w)  -> bf16
    rmsnorm1024_kernel<<<NTOK, 256, 0, stream>>>(xbuf, post_norm_w, h2);
    // 9. gu = h2 @ Wgu^T  (fused gate+up, N=5504)
    gemm_bf<0><<<dim3(43, 16), 256, 0, stream>>>(h2, (const bf16*)Wgu, gu,
        nullptr, NTOK, 2 * INTER, DMODEL);
    // 10. act = bf16(silu(g) * u)
    silu_mul_kernel<<<(NTOK * INTER) / 256, 256, 0, stream>>>(gu, act, NTOK * INTER);
    // 11. out = x + act @ Wdn^T   (f32 to d_out)
    gemm_bf<1><<<dim3(8, 16), 256, 0, stream>>>(act, (const bf16*)Wdn, out,
        xbuf, NTOK, DMODEL, INTER);
}

// Round 9
// 464.895 us; speedup vs baseline: 6.1461x; 1.1465x over previous
//
#include <hip/hip_runtime.h>
#include <hip/hip_bf16.h>

// ---- problem constants ----
#define SEQLEN   1024
#define NTOK     2048          // BATCH * SEQLEN
#define DMODEL   1024
#define DSTATE   128
#define DINNER   2048
#define NHEADS   32
#define HEADDIM  64
#define CONVDIM  2304          // DINNER + 2*DSTATE
#define DINPROJ  4384          // 2*DINNER + 2*DSTATE + NHEADS
#define INTER    2752
#define Q        64            // scan chunk length
#define NCHUNK   16            // SEQLEN / Q

typedef __hip_bfloat16 bf16;
typedef unsigned short ushort_t;
typedef __attribute__((ext_vector_type(8))) short bf16x8;
typedef __attribute__((ext_vector_type(4))) float f32x4;
typedef __attribute__((ext_vector_type(4))) unsigned short u16x4;

__device__ __forceinline__ float bf2f(bf16 x) { return __bfloat162float(x); }
__device__ __forceinline__ float bfu2f(ushort_t u) {
    return __uint_as_float(((unsigned)u) << 16);
}
__device__ __forceinline__ ushort_t f2bfu(float x) {
    union { bf16 h; ushort_t u; } c; c.h = __float2bfloat16(x); return c.u;
}
__device__ __forceinline__ unsigned packbf2(float x, float y) {
    return ((unsigned)f2bfu(y) << 16) | f2bfu(x);
}

__device__ __forceinline__ void glds16(const void* g, void* l) {
    __builtin_amdgcn_global_load_lds(
        (const __attribute__((address_space(1))) void*)g,
        (__attribute__((address_space(3))) void*)l, 16, 0, 0);
}

__device__ inline float block_reduce_sum(float v) {
    __shared__ float red[4];
    #pragma unroll
    for (int off = 32; off >= 1; off >>= 1) v += __shfl_down(v, off);
    int lane = threadIdx.x & 63, w = threadIdx.x >> 6;
    if (lane == 0) red[w] = v;
    __syncthreads();
    return red[0] + red[1] + red[2] + red[3];
}

// ---- fp32 -> bf16 weight convert (4 elems/thread) ----
__global__ __launch_bounds__(256) void f2bf_kernel(
    const float* __restrict__ src, ushort_t* __restrict__ dst, int n)
{
    const int i = (blockIdx.x * 256 + threadIdx.x) * 4;
    if (i < n) {
        const f32x4 v = *(const f32x4*)(src + i);
        u16x4 o;
        #pragma unroll
        for (int k = 0; k < 4; k++) o[k] = f2bfu(v[k]);
        *(u16x4*)(dst + i) = o;
    }
}

// ---- RMSNorm over 1024 dims (fp32 in, fp32 weights) -> bf16 out ----
__global__ __launch_bounds__(256) void rmsnorm1024_kernel(
    const float* __restrict__ x, const float* __restrict__ w, bf16* __restrict__ out)
{
    const int token = blockIdx.x, t = threadIdx.x;
    float v[4]; float ss = 0.f;
    #pragma unroll
    for (int i = 0; i < 4; i++) {
        v[i] = x[(size_t)token * DMODEL + t * 4 + i];
        ss += v[i] * v[i];
    }
    ss = block_reduce_sum(ss);
    const float scale = rsqrtf(ss * (1.0f / DMODEL) + 1e-6f);
    #pragma unroll
    for (int i = 0; i < 4; i++)
        out[(size_t)token * DMODEL + t * 4 + i] =
            __float2bfloat16(v[i] * scale * w[t * 4 + i]);
}

// ---- MFMA GEMM (async staging): C(MxN f32) = A(MxK bf16) @ W(NxK bf16)^T ----
template <int EPI>
__global__ __launch_bounds__(256) void gemm_bf(
    const bf16* __restrict__ A, const bf16* __restrict__ W,
    float* __restrict__ Cf, const float* __restrict__ resid_f,
    int M, int N, int K)
{
    __shared__ ushort_t As[128 * 32];
    __shared__ ushort_t Bs[128 * 32];
    const int tid = threadIdx.x;
    const int w = tid >> 6, lane = tid & 63;
    const int m0 = blockIdx.y * 128, n0 = blockIdx.x * 128;

    const int srow = tid >> 2;
    const int skof = (tid & 3) * 8;
    const bf16* Ag0 = A + (size_t)(m0 + srow) * K + skof;
    const bf16* Ag1 = Ag0 + (size_t)64 * K;
    const int nr0 = n0 + srow, nr1 = n0 + 64 + srow;
    const bf16* Wg0 = W + (size_t)(nr0 < N ? nr0 : 0) * K + skof;
    const bf16* Wg1 = W + (size_t)(nr1 < N ? nr1 : 0) * K + skof;
    ushort_t* lA0 = &As[w * 512];
    ushort_t* lA1 = &As[2048 + w * 512];
    ushort_t* lB0 = &Bs[w * 512];
    ushort_t* lB1 = &Bs[2048 + w * 512];

    const int wy = w >> 1, wx = w & 1;
    const int fr = lane & 15;
    const int fk = (lane >> 4) * 8;
    f32x4 acc[4][4];
    #pragma unroll
    for (int i = 0; i < 4; i++)
        #pragma unroll
        for (int j = 0; j < 4; j++)
            acc[i][j] = (f32x4){0.f, 0.f, 0.f, 0.f};

    for (int k0 = 0; k0 < K; k0 += 32) {
        __syncthreads();
        glds16(Ag0 + k0, lA0);
        glds16(Ag1 + k0, lA1);
        glds16(Wg0 + k0, lB0);
        glds16(Wg1 + k0, lB1);
        __syncthreads();
        bf16x8 af[4], bfv[4];
        #pragma unroll
        for (int i = 0; i < 4; i++)
            af[i] = *(const bf16x8*)&As[(wy * 64 + i * 16 + fr) * 32 + fk];
        #pragma unroll
        for (int j = 0; j < 4; j++)
            bfv[j] = *(const bf16x8*)&Bs[(wx * 64 + j * 16 + fr) * 32 + fk];
        #pragma unroll
        for (int i = 0; i < 4; i++)
            #pragma unroll
            for (int j = 0; j < 4; j++)
                acc[i][j] = __builtin_amdgcn_mfma_f32_16x16x32_bf16(
                    af[i], bfv[j], acc[i][j], 0, 0, 0);
    }

    #pragma unroll
    for (int i = 0; i < 4; i++) {
        #pragma unroll
        for (int j = 0; j < 4; j++) {
            const int mb = m0 + wy * 64 + i * 16 + (lane >> 4) * 4;
            const int nn = n0 + wx * 64 + j * 16 + (lane & 15);
            if (nn < N) {
                #pragma unroll
                for (int r = 0; r < 4; r++) {
                    const size_t idx = (size_t)(mb + r) * N + nn;
                    float v = acc[i][j][r];
                    if (EPI == 1) v += resid_f[idx];
                    Cf[idx] = v;
                }
            }
        }
    }
}

// ---- depthwise causal conv (k=4) + bias + silu over xBC channels ----
__global__ __launch_bounds__(256) void conv_silu_kernel(
    const float* __restrict__ zx, const float* __restrict__ cw,
    const float* __restrict__ cb, float* __restrict__ out)
{
    const int idx = blockIdx.x * 256 + threadIdx.x;
    if (idx >= NTOK * CONVDIM) return;
    const int c = idx % CONVDIM;
    const int token = idx / CONVDIM;
    const int l = token & (SEQLEN - 1);
    float acc = cb[c];
    #pragma unroll
    for (int k = 0; k < 4; k++) {
        const int ls = l - 3 + k;
        if (ls >= 0)
            acc += zx[(size_t)(token - 3 + k) * DINPROJ + DINNER + c] * cw[c * 4 + k];
    }
    out[(size_t)token * CONVDIM + c] = acc / (1.f + expf(-acc));   // silu
}

// ---- dt = softplus(dt_raw + dt_bias) ----
__global__ __launch_bounds__(256) void dt_softplus_kernel(
    const float* __restrict__ zx, const float* __restrict__ dtb,
    float* __restrict__ out)
{
    const int idx = blockIdx.x * 256 + threadIdx.x;   // NTOK*NHEADS
    const int h = idx & (NHEADS - 1);
    const int token = idx >> 5;
    float v = zx[(size_t)token * DINPROJ + (DINNER + CONVDIM) + h] + dtb[h];
    out[idx] = (v > 20.f) ? v : log1pf(expf(v));
}

// ================= chunked scan =================
// Phase A: per-chunk state S_c[p,n] = sum_l exp(cumQ-cum[l]) dt_l x[l,p] B[l,n]
__global__ __launch_bounds__(256) void chunk_state_kernel(
    const float* __restrict__ convb, const float* __restrict__ dtb,
    const float* __restrict__ A_log, float* __restrict__ ccum,
    ushort_t* __restrict__ Sbuf)
{
    const int bx = blockIdx.x;
    const int bh = bx >> 4, c = bx & 15;
    const int b = bh >> 5, h = bh & 31;
    const int t = threadIdx.x;
    const int p = t >> 2, q = t & 3;
    const int tok0 = b * SEQLEN + c * Q;
    const float A = -expf(A_log[h]);

    __shared__ float sX[Q * 66];
    __shared__ float sB[Q * 132];
    __shared__ float sW[Q];

    for (int i = t; i < Q * HEADDIM; i += 256) {
        const int row = i >> 6, col = i & 63;
        sX[row * 66 + col] = convb[(size_t)(tok0 + row) * CONVDIM + h * HEADDIM + col];
    }
    for (int i = t; i < Q * DSTATE; i += 256) {
        const int row = i >> 7, col = i & 127;
        sB[row * 132 + col] = convb[(size_t)(tok0 + row) * CONVDIM + DINNER + col];
    }
    if (t < Q) {
        const float d = dtb[(size_t)(tok0 + t) * NHEADS + h];
        float s = d;
        #pragma unroll
        for (int off = 1; off < 64; off <<= 1) {
            const float up = __shfl_up(s, off);
            if (t >= off) s += up;
        }
        const float total = __shfl(s, 63);
        sW[t] = expf(A * (total - s)) * d;     // arg <= 0
        if (t == 63) ccum[bh * NCHUNK + c] = A * total;
    }
    __syncthreads();

    float acc[32] = {};
    for (int l = 0; l < Q; l++) {
        const float wx = sW[l] * sX[l * 66 + p];
        #pragma unroll
        for (int jj = 0; jj < 8; jj++) {
            const f32x4 bv = *(const f32x4*)&sB[l * 132 + q * 4 + 16 * jj];
            #pragma unroll
            for (int k = 0; k < 4; k++)
                acc[jj * 4 + k] += wx * bv[k];
        }
    }
    const size_t slot = ((size_t)(bh * NCHUNK + c) * 64 + p) * 128;
    #pragma unroll
    for (int jj = 0; jj < 8; jj++) {
        u16x4 sv;
        #pragma unroll
        for (int k = 0; k < 4; k++) sv[k] = f2bfu(acc[jj * 4 + k]);
        *(u16x4*)&Sbuf[slot + q * 4 + 16 * jj] = sv;
    }
}

// Phase B: sequential stitch; writes incoming H_c into slot c.
__global__ __launch_bounds__(256) void stitch_kernel(
    const float* __restrict__ ccum, ushort_t* __restrict__ Sbuf)
{
    const int bh = blockIdx.x;
    const int t = threadIdx.x, p = t >> 2, q = t & 3;
    float H[32];
    #pragma unroll
    for (int j = 0; j < 32; j++) H[j] = 0.f;
    for (int c = 0; c < NCHUNK; c++) {
        const float P = expf(ccum[bh * NCHUNK + c]);
        const size_t slot = ((size_t)(bh * NCHUNK + c) * 64 + p) * 128;
        #pragma unroll
        for (int jj = 0; jj < 8; jj++) {
            const u16x4 sv4 = *(const u16x4*)&Sbuf[slot + q * 4 + 16 * jj];
            u16x4 hv4;
            #pragma unroll
            for (int k = 0; k < 4; k++) hv4[k] = f2bfu(H[jj * 4 + k]);
            *(u16x4*)&Sbuf[slot + q * 4 + 16 * jj] = hv4;
            #pragma unroll
            for (int k = 0; k < 4; k++)
                H[jj * 4 + k] = P * H[jj * 4 + k] + bfu2f(sv4[k]);
        }
    }
}

// Phase C (MFMA form): Y = mask(C@B^T)@X + (exp(cum)·C)@H^T + D·X
// grid: 1024 = bh*16 + c, 256 thr (4 waves, each 2x2 of 16x16 tiles)
__global__ __launch_bounds__(256) void chunk_scan_mfma_kernel(
    const float* __restrict__ convb, const float* __restrict__ dtb,
    const float* __restrict__ A_log, const float* __restrict__ Dh,
    const ushort_t* __restrict__ Sbuf, bf16* __restrict__ ybuf)
{
    const int bx = blockIdx.x;
    const int bh = bx >> 4, c = bx & 15;
    const int b = bh >> 5, h = bh & 31;
    const int t = threadIdx.x;
    const int w = t >> 6, lane = t & 63;
    const int wy = w >> 1, wx = w & 1;
    const int fr = lane & 15;              // fragment row
    const int fk = (lane >> 4) * 8;        // fragment k offset
    const int cr = (lane >> 4) * 4;        // C/D row base
    const int tok0 = b * SEQLEN + c * Q;
    const float A = -expf(A_log[h]);
    const float Dv = Dh[h];

    __shared__ ushort_t sB[64 * 136];      // [l][n]
    __shared__ ushort_t sC[64 * 136];      // [l][n] (later scaled by exp(cum_l))
    __shared__ ushort_t sH[64 * 136];      // [p][n]
    __shared__ ushort_t sXT[64 * 72];      // [p][l]
    __shared__ ushort_t sM[64 * 72];       // [l][j]
    __shared__ float    sCum[64];
    __shared__ float    sDtv[64];

    // stage B, C (bf16 pairs)
    for (int i = t; i < 64 * 64; i += 256) {
        const int row = i >> 6, col = (i & 63) * 2;
        const float* srcB = &convb[(size_t)(tok0 + row) * CONVDIM + DINNER + col];
        *(unsigned*)&sB[row * 136 + col] = packbf2(srcB[0], srcB[1]);
        const float* srcC = &convb[(size_t)(tok0 + row) * CONVDIM + DINNER + DSTATE + col];
        *(unsigned*)&sC[row * 136 + col] = packbf2(srcC[0], srcC[1]);
    }
    // stage X transposed: sXT[p][l]
    for (int i = t; i < 64 * 32; i += 256) {
        const int p = i >> 5, l0 = (i & 31) * 2;
        const float x0 = convb[(size_t)(tok0 + l0)     * CONVDIM + h * HEADDIM + p];
        const float x1 = convb[(size_t)(tok0 + l0 + 1) * CONVDIM + h * HEADDIM + p];
        *(unsigned*)&sXT[p * 72 + l0] = packbf2(x0, x1);
    }
    // stage H from Sbuf (bf16 already)
    {
        const size_t slot = (size_t)(bh * NCHUNK + c) * 64 * 128;
        for (int i = t * 4; i < 64 * 128; i += 1024) {
            const int row = i >> 7, col = i & 127;
            *(u16x4*)&sH[row * 136 + col] = *(const u16x4*)&Sbuf[slot + row * 128 + col];
        }
    }
    // dt + inclusive cumsum (wave 0)
    if (t < 64) {
        const float d = dtb[(size_t)(tok0 + t) * NHEADS + h];
        float s = d;
        #pragma unroll
        for (int off = 1; off < 64; off <<= 1) {
            const float up = __shfl_up(s, off);
            if (t >= off) s += up;
        }
        sCum[t] = A * s;
        sDtv[t] = d;
    }
    __syncthreads();

    // GEMM1: G = C @ B^T  (l x j, K=n=128)
    f32x4 accg[2][2];
    #pragma unroll
    for (int i = 0; i < 2; i++)
        #pragma unroll
        for (int j = 0; j < 2; j++)
            accg[i][j] = (f32x4){0.f, 0.f, 0.f, 0.f};
    #pragma unroll
    for (int k0 = 0; k0 < 128; k0 += 32) {
        bf16x8 af[2], bfv[2];
        #pragma unroll
        for (int i = 0; i < 2; i++)
            af[i] = *(const bf16x8*)&sC[(wy * 32 + i * 16 + fr) * 136 + fk + k0];
        #pragma unroll
        for (int j = 0; j < 2; j++)
            bfv[j] = *(const bf16x8*)&sB[(wx * 32 + j * 16 + fr) * 136 + fk + k0];
        #pragma unroll
        for (int i = 0; i < 2; i++)
            #pragma unroll
            for (int j = 0; j < 2; j++)
                accg[i][j] = __builtin_amdgcn_mfma_f32_16x16x32_bf16(
                    af[i], bfv[j], accg[i][j], 0, 0, 0);
    }
    __syncthreads();   // all GEMM1 reads of sC done before scaling

    // write masked M to sM; scale sC rows by exp(cum_l)
    #pragma unroll
    for (int i = 0; i < 2; i++) {
        #pragma unroll
        for (int j = 0; j < 2; j++) {
            #pragma unroll
            for (int r = 0; r < 4; r++) {
                const int l  = wy * 32 + i * 16 + cr + r;
                const int jc = wx * 32 + j * 16 + fr;
                const float v = (jc <= l)
                    ? accg[i][j][r] * expf(sCum[l] - sCum[jc]) * sDtv[jc] : 0.f;
                sM[l * 72 + jc] = f2bfu(v);
            }
        }
    }
    for (int i = t; i < 64 * 32; i += 256) {
        const int row = i >> 5, col = (i & 31) * 4;
        const float sc = expf(sCum[row]);
        u16x4 v = *(const u16x4*)&sC[row * 136 + col];
        #pragma unroll
        for (int k = 0; k < 4; k++) v[k] = f2bfu(bfu2f(v[k]) * sc);
        *(u16x4*)&sC[row * 136 + col] = v;
    }
    __syncthreads();

    // GEMM2: Y = M @ X  +  (scaled C) @ H^T   (l x p)
    f32x4 accy[2][2];
    #pragma unroll
    for (int i = 0; i < 2; i++)
        #pragma unroll
        for (int j = 0; j < 2; j++)
            accy[i][j] = (f32x4){0.f, 0.f, 0.f, 0.f};
    #pragma unroll
    for (int k0 = 0; k0 < 64; k0 += 32) {
        bf16x8 af[2], bfv[2];
        #pragma unroll
        for (int i = 0; i < 2; i++)
            af[i] = *(const bf16x8*)&sM[(wy * 32 + i * 16 + fr) * 72 + fk + k0];
        #pragma unroll
        for (int j = 0; j < 2; j++)
            bfv[j] = *(const bf16x8*)&sXT[(wx * 32 + j * 16 + fr) * 72 + fk + k0];
        #pragma unroll
        for (int i = 0; i < 2; i++)
            #pragma unroll
            for (int j = 0; j < 2; j++)
                accy[i][j] = __builtin_amdgcn_mfma_f32_16x16x32_bf16(
                    af[i], bfv[j], accy[i][j], 0, 0, 0);
    }
    #pragma unroll
    for (int k0 = 0; k0 < 128; k0 += 32) {
        bf16x8 af[2], bfv[2];
        #pragma unroll
        for (int i = 0; i < 2; i++)
            af[i] = *(const bf16x8*)&sC[(wy * 32 + i * 16 + fr) * 136 + fk + k0];
        #pragma unroll
        for (int j = 0; j < 2; j++)
            bfv[j] = *(const bf16x8*)&sH[(wx * 32 + j * 16 + fr) * 136 + fk + k0];
        #pragma unroll
        for (int i = 0; i < 2; i++)
            #pragma unroll
            for (int j = 0; j < 2; j++)
                accy[i][j] = __builtin_amdgcn_mfma_f32_16x16x32_bf16(
                    af[i], bfv[j], accy[i][j], 0, 0, 0);
    }

    // epilogue: + D*x, store bf16
    #pragma unroll
    for (int i = 0; i < 2; i++) {
        #pragma unroll
        for (int j = 0; j < 2; j++) {
            #pragma unroll
            for (int r = 0; r < 4; r++) {
                const int l = wy * 32 + i * 16 + cr + r;
                const int p = wx * 32 + j * 16 + fr;
                const float x = bfu2f(sXT[p * 72 + l]);
                ybuf[(size_t)(tok0 + l) * DINNER + h * HEADDIM + p] =
                    __float2bfloat16(accy[i][j][r] + Dv * x);
            }
        }
    }
}

// ---- ynorm = rmsnorm(y * silu(z)) over 2048 dims -> bf16 (y is bf16) ----
__global__ __launch_bounds__(256) void gated_rmsnorm_kernel(
    const bf16* __restrict__ y, const float* __restrict__ zx,
    const float* __restrict__ w, bf16* __restrict__ out)
{
    const int token = blockIdx.x, t = threadIdx.x;
    const bf16* yr = y + (size_t)token * DINNER;
    const float* zr = zx + (size_t)token * DINPROJ;   // z = first 2048
    float v[8]; float ss = 0.f;
    #pragma unroll
    for (int i = 0; i < 8; i++) {
        const int idx = t * 8 + i;
        const float zz = zr[idx];
        const float val = bf2f(yr[idx]) * (zz / (1.f + expf(-zz)));
        v[i] = val; ss += val * val;
    }
    ss = block_reduce_sum(ss);
    const float scale = rsqrtf(ss * (1.0f / DINNER) + 1e-6f);
    #pragma unroll
    for (int i = 0; i < 8; i++) {
        const int idx = t * 8 + i;
        out[(size_t)token * DINNER + idx] =
            __float2bfloat16(v[i] * scale * w[idx]);
    }
}

// ---- act = bf16(silu(g) * u) from combined gu (2048 x 5504) ----
__global__ __launch_bounds__(256) void silu_mul_kernel(
    const float* __restrict__ gu, bf16* __restrict__ act, int n)
{
    const int i = blockIdx.x * 256 + threadIdx.x;
    if (i < n) {
        const int m = i / INTER, j = i - m * INTER;
        const float g = gu[(size_t)m * (2 * INTER) + j];
        const float u = gu[(size_t)m * (2 * INTER) + INTER + j];
        act[i] = __float2bfloat16((g / (1.f + expf(-g))) * u);
    }
}

extern "C" void kernel_launch(void* const* d_in, const int* in_sizes, int n_in,
                              void* d_out, int out_size, void* d_ws, size_t ws_size,
                              hipStream_t stream) {
    const float* hidden     = (const float*)d_in[0];
    const float* norm_w     = (const float*)d_in[1];
    const float* in_proj_w  = (const float*)d_in[2];
    const float* conv_w     = (const float*)d_in[3];
    const float* conv_b     = (const float*)d_in[4];
    const float* dt_bias    = (const float*)d_in[5];
    const float* A_log      = (const float*)d_in[6];
    const float* Dh         = (const float*)d_in[7];
    const float* ssm_norm_w = (const float*)d_in[8];
    const float* out_proj_w = (const float*)d_in[9];
    const float* post_norm_w= (const float*)d_in[10];
    const float* gate_w     = (const float*)d_in[11];
    const float* up_w       = (const float*)d_in[12];
    const float* down_w     = (const float*)d_in[13];
    float* out = (float*)d_out;

    // ---- workspace layout (fl units; peak = 23,200,768 fl = 92.8 MB) ----
    float* ws = (float*)d_ws;
    bf16*  h_norm = (bf16*)(ws);                 // [0, 1,048,576)
    float* zx     = ws + 1048576;                // [1,048,576, 10,027,008)
    float* convb  = ws + 10027008;               // [10,027,008, 14,745,600)
    float* dtb    = ws + 14745600;               // [14,745,600, 14,811,136)
    float* ccum   = ws + 14811136;               // 1024 fl
    ushort_t* Sbuf= (ushort_t*)(ws + 14812160);  // [14,812,160, 19,006,464) bf16
    float* xbuf   = ws + 19006464;               // [19,006,464, 21,103,616)
    bf16*  ybuf   = (bf16*)(ws + 21103616);      // [21,103,616, 22,152,192)
    bf16*  ynorm  = (bf16*)(ws + 22152192);      // [22,152,192, 23,200,768)
    // just-in-time bf16 weights in dead regions:
    ushort_t* Wip = (ushort_t*)(ws + 10027008);  // convb region, dead before conv
    ushort_t* Wop = (ushort_t*)(ws + 1048576);   // zx region, after z consumed
    ushort_t* Wgu = (ushort_t*)(ws + 2097152);   // gate rows 0..2751, up 2752..5503
    ushort_t* Wdn = (ushort_t*)(ws + 4915200);
    float* gu     = ws + 6324224;                // [6,324,224, 17,596,416) f32 2048x5504
    bf16*  h2     = h_norm;                      // reuse
    bf16*  act    = (bf16*)(ws + 1048576);       // over Wop/Wgu-head (dead by then)

    // 0a. Wip = bf16(in_proj_w)
    f2bf_kernel<<<4384, 256, 0, stream>>>(in_proj_w, Wip, DINPROJ * DMODEL);
    // 1. h = rmsnorm(hidden, norm_w)  -> bf16
    rmsnorm1024_kernel<<<NTOK, 256, 0, stream>>>(hidden, norm_w, h_norm);
    // 2. zxbcdt = h @ Wip^T   (f32 out)
    gemm_bf<0><<<dim3(35, 16), 256, 0, stream>>>(h_norm, (const bf16*)Wip, zx,
        nullptr, NTOK, DINPROJ, DMODEL);
    // 3. conv(k=4) + bias + silu on xBC
    conv_silu_kernel<<<(NTOK * CONVDIM) / 256, 256, 0, stream>>>(zx, conv_w, conv_b, convb);
    // 4. dt = softplus(dt_raw + dt_bias)
    dt_softplus_kernel<<<(NTOK * NHEADS) / 256, 256, 0, stream>>>(zx, dt_bias, dtb);
    // 5. chunked selective scan -> ybuf (bf16)
    chunk_state_kernel<<<1024, 256, 0, stream>>>(convb, dtb, A_log, ccum, Sbuf);
    stitch_kernel<<<64, 256, 0, stream>>>(ccum, Sbuf);
    chunk_scan_mfma_kernel<<<1024, 256, 0, stream>>>(convb, dtb, A_log, Dh, Sbuf, ybuf);
    // 6. ynorm = rmsnorm(y * silu(z), ssm_norm_w)  -> bf16 (last use of zx)
    gated_rmsnorm_kernel<<<NTOK, 256, 0, stream>>>(ybuf, zx, ssm_norm_w, ynorm);
    // 6b. convert remaining weights into dead zx region
    f2bf_kernel<<<2048, 256, 0, stream>>>(out_proj_w, Wop, DMODEL * DINNER);
    f2bf_kernel<<<2752, 256, 0, stream>>>(gate_w, Wgu, INTER * DMODEL);
    f2bf_kernel<<<2752, 256, 0, stream>>>(up_w, Wgu + INTER * DMODEL, INTER * DMODEL);
    f2bf_kernel<<<2752, 256, 0, stream>>>(down_w, Wdn, DMODEL * INTER);
    // 7. x = hidden + ynorm @ Wop^T  (f32)
    gemm_bf<1><<<dim3(8, 16), 256, 0, stream>>>(ynorm, (const bf16*)Wop, xbuf,
        hidden, NTOK, DMODEL, DINNER);
    // 8. h2 = rmsnorm(x, post_norm_w)  -> bf16
    rmsnorm1024_kernel<<<NTOK, 256, 0, stream>>>(xbuf, post_norm_w, h2);
    // 9. gu = h2 @ Wgu^T  (fused gate+up, N=5504)
    gemm_bf<0><<<dim3(43, 16), 256, 0, stream>>>(h2, (const bf16*)Wgu, gu,
        nullptr, NTOK, 2 * INTER, DMODEL);
    // 10. act = bf16(silu(g) * u)
    silu_mul_kernel<<<(NTOK * INTER) / 256, 256, 0, stream>>>(gu, act, NTOK * INTER);
    // 11. out = x + act @ Wdn^T   (f32 to d_out)
    gemm_bf<1><<<dim3(8, 16), 256, 0, stream>>>(act, (const bf16*)Wdn, out,
        xbuf, NTOK, DMODEL, INTER);
}

// Round 10
// 411.132 us; speedup vs baseline: 6.9498x; 1.1308x over previous
//
#include <hip/hip_runtime.h>
#include <hip/hip_bf16.h>

// ---- problem constants ----
#define SEQLEN   1024
#define NTOK     2048          // BATCH * SEQLEN
#define DMODEL   1024
#define DSTATE   128
#define DINNER   2048
#define NHEADS   32
#define HEADDIM  64
#define CONVDIM  2304          // DINNER + 2*DSTATE
#define DINPROJ  4384          // 2*DINNER + 2*DSTATE + NHEADS
#define INTER    2752
#define Q        64            // scan chunk length
#define NCHUNK   16            // SEQLEN / Q

typedef __hip_bfloat16 bf16;
typedef unsigned short ushort_t;
typedef __attribute__((ext_vector_type(8))) short bf16x8;
typedef __attribute__((ext_vector_type(4))) float f32x4;
typedef __attribute__((ext_vector_type(4))) unsigned short u16x4;

__device__ __forceinline__ float bf2f(bf16 x) { return __bfloat162float(x); }
__device__ __forceinline__ float bfu2f(ushort_t u) {
    return __uint_as_float(((unsigned)u) << 16);
}
__device__ __forceinline__ ushort_t f2bfu(float x) {
    union { bf16 h; ushort_t u; } c; c.h = __float2bfloat16(x); return c.u;
}

__device__ __forceinline__ void glds16(const void* g, void* l) {
    __builtin_amdgcn_global_load_lds(
        (const __attribute__((address_space(1))) void*)g,
        (__attribute__((address_space(3))) void*)l, 16, 0, 0);
}

__device__ inline float block_reduce_sum(float v) {
    __shared__ float red[4];
    #pragma unroll
    for (int off = 32; off >= 1; off >>= 1) v += __shfl_down(v, off);
    int lane = threadIdx.x & 63, w = threadIdx.x >> 6;
    if (lane == 0) red[w] = v;
    __syncthreads();
    return red[0] + red[1] + red[2] + red[3];
}

// ---- fp32 -> bf16 weight convert (4 elems/thread) ----
__global__ __launch_bounds__(256) void f2bf_kernel(
    const float* __restrict__ src, ushort_t* __restrict__ dst, int n)
{
    const int i = (blockIdx.x * 256 + threadIdx.x) * 4;
    if (i < n) {
        const f32x4 v = *(const f32x4*)(src + i);
        u16x4 o;
        #pragma unroll
        for (int k = 0; k < 4; k++) o[k] = f2bfu(v[k]);
        *(u16x4*)(dst + i) = o;
    }
}

// ---- RMSNorm over 1024 dims (fp32 in, fp32 weights) -> bf16 out ----
__global__ __launch_bounds__(256) void rmsnorm1024_kernel(
    const float* __restrict__ x, const float* __restrict__ w, bf16* __restrict__ out)
{
    const int token = blockIdx.x, t = threadIdx.x;
    float v[4]; float ss = 0.f;
    #pragma unroll
    for (int i = 0; i < 4; i++) {
        v[i] = x[(size_t)token * DMODEL + t * 4 + i];
        ss += v[i] * v[i];
    }
    ss = block_reduce_sum(ss);
    const float scale = rsqrtf(ss * (1.0f / DMODEL) + 1e-6f);
    #pragma unroll
    for (int i = 0; i < 4; i++)
        out[(size_t)token * DMODEL + t * 4 + i] =
            __float2bfloat16(v[i] * scale * w[t * 4 + i]);
}

// ---- MFMA GEMM (async staging): C(M x N f32) = A(MxK bf16) @ W(NxK bf16)^T ----
// MT x 128 tile, BK=32, 256 thr (4 waves 2x2), global_load_lds width=16
// MT in {128, 64}. EPI 0: Cf=acc ; EPI 1: Cf=acc+resid_f
template <int EPI, int MT>
__global__ __launch_bounds__(256) void gemm_bf(
    const bf16* __restrict__ A, const bf16* __restrict__ W,
    float* __restrict__ Cf, const float* __restrict__ resid_f,
    int M, int N, int K)
{
    __shared__ ushort_t As[MT * 32];
    __shared__ ushort_t Bs[128 * 32];
    const int tid = threadIdx.x;
    const int w = tid >> 6, lane = tid & 63;
    const int m0 = blockIdx.y * MT, n0 = blockIdx.x * 128;

    const int srow = tid >> 2;
    const int skof = (tid & 3) * 8;
    const bf16* Ag0 = A + (size_t)(m0 + srow) * K + skof;
    const bf16* Ag1 = Ag0 + (size_t)64 * K;          // only if MT==128
    const int nr0 = n0 + srow, nr1 = n0 + 64 + srow;
    const bf16* Wg0 = W + (size_t)(nr0 < N ? nr0 : 0) * K + skof;
    const bf16* Wg1 = W + (size_t)(nr1 < N ? nr1 : 0) * K + skof;
    ushort_t* lA0 = &As[w * 512];
    ushort_t* lA1 = &As[2048 + w * 512];
    ushort_t* lB0 = &Bs[w * 512];
    ushort_t* lB1 = &Bs[2048 + w * 512];

    const int wy = w >> 1, wx = w & 1;
    const int fr = lane & 15;
    const int fk = (lane >> 4) * 8;
    constexpr int MI = MT / 32;
    f32x4 acc[MI][4];
    #pragma unroll
    for (int i = 0; i < MI; i++)
        #pragma unroll
        for (int j = 0; j < 4; j++)
            acc[i][j] = (f32x4){0.f, 0.f, 0.f, 0.f};

    for (int k0 = 0; k0 < K; k0 += 32) {
        __syncthreads();
        glds16(Ag0 + k0, lA0);
        if (MT == 128) glds16(Ag1 + k0, lA1);
        glds16(Wg0 + k0, lB0);
        glds16(Wg1 + k0, lB1);
        __syncthreads();
        bf16x8 af[MI], bfv[4];
        #pragma unroll
        for (int i = 0; i < MI; i++)
            af[i] = *(const bf16x8*)&As[(wy * (MT / 2) + i * 16 + fr) * 32 + fk];
        #pragma unroll
        for (int j = 0; j < 4; j++)
            bfv[j] = *(const bf16x8*)&Bs[(wx * 64 + j * 16 + fr) * 32 + fk];
        #pragma unroll
        for (int i = 0; i < MI; i++)
            #pragma unroll
            for (int j = 0; j < 4; j++)
                acc[i][j] = __builtin_amdgcn_mfma_f32_16x16x32_bf16(
                    af[i], bfv[j], acc[i][j], 0, 0, 0);
    }

    // C/D layout: col = lane&15, row = (lane>>4)*4 + reg
    #pragma unroll
    for (int i = 0; i < MI; i++) {
        #pragma unroll
        for (int j = 0; j < 4; j++) {
            const int mb = m0 + wy * (MT / 2) + i * 16 + (lane >> 4) * 4;
            const int nn = n0 + wx * 64 + j * 16 + (lane & 15);
            if (nn < N) {
                #pragma unroll
                for (int r = 0; r < 4; r++) {
                    const size_t idx = (size_t)(mb + r) * N + nn;
                    float v = acc[i][j][r];
                    if (EPI == 1) v += resid_f[idx];
                    Cf[idx] = v;
                }
            }
        }
    }
}

// ---- depthwise causal conv (k=4) + bias + silu over xBC -> bf16 out ----
__global__ __launch_bounds__(256) void conv_silu_kernel(
    const float* __restrict__ zx, const float* __restrict__ cw,
    const float* __restrict__ cb, ushort_t* __restrict__ out)
{
    const int idx = blockIdx.x * 256 + threadIdx.x;
    if (idx >= NTOK * CONVDIM) return;
    const int c = idx % CONVDIM;
    const int token = idx / CONVDIM;
    const int l = token & (SEQLEN - 1);
    float acc = cb[c];
    #pragma unroll
    for (int k = 0; k < 4; k++) {
        const int ls = l - 3 + k;
        if (ls >= 0)
            acc += zx[(size_t)(token - 3 + k) * DINPROJ + DINNER + c] * cw[c * 4 + k];
    }
    out[(size_t)token * CONVDIM + c] = f2bfu(acc / (1.f + expf(-acc)));   // silu
}

// ---- dt = softplus(dt_raw + dt_bias) ----
__global__ __launch_bounds__(256) void dt_softplus_kernel(
    const float* __restrict__ zx, const float* __restrict__ dtb,
    float* __restrict__ out)
{
    const int idx = blockIdx.x * 256 + threadIdx.x;   // NTOK*NHEADS
    const int h = idx & (NHEADS - 1);
    const int token = idx >> 5;
    float v = zx[(size_t)token * DINPROJ + (DINNER + CONVDIM) + h] + dtb[h];
    out[idx] = (v > 20.f) ? v : log1pf(expf(v));
}

// ================= chunked scan =================
// Phase A (MFMA): S[p,n] = sum_l (w_l x[l,p]) B[l,n],  w_l = exp(cumQ-cum_l)*dt_l
// grid: 1024 = bh*16 + c
__global__ __launch_bounds__(256) void chunk_state_kernel(
    const ushort_t* __restrict__ cvb, const float* __restrict__ dtb,
    const float* __restrict__ A_log, float* __restrict__ ccum,
    ushort_t* __restrict__ Sbuf)
{
    const int bx = blockIdx.x;
    const int bh = bx >> 4, c = bx & 15;
    const int b = bh >> 5, h = bh & 31;
    const int t = threadIdx.x;
    const int w = t >> 6, lane = t & 63;
    const int wy = w >> 1, wx = w & 1;
    const int fr = lane & 15, fk = (lane >> 4) * 8, cr = (lane >> 4) * 4;
    const int tok0 = b * SEQLEN + c * Q;
    const float A = -expf(A_log[h]);

    __shared__ ushort_t sXT[64 * 88];    // [p][l], weighted; pitch 88 (16B-aligned rows)
    __shared__ ushort_t sBT[128 * 88];   // [n][l]
    __shared__ float sW[64];

    if (t < 64) {
        const float d = dtb[(size_t)(tok0 + t) * NHEADS + h];
        float s = d;
        #pragma unroll
        for (int off = 1; off < 64; off <<= 1) {
            const float up = __shfl_up(s, off);
            if (t >= off) s += up;
        }
        const float total = __shfl(s, 63);
        sW[t] = expf(A * (total - s)) * d;     // arg <= 0
        if (t == 63) ccum[bh * NCHUNK + c] = A * total;
    }
    __syncthreads();

    // stage weighted X^T and B^T (transposed, u16)
    for (int i = t; i < 64 * 64; i += 256) {
        const int l = i >> 6, p = i & 63;
        const float v = bfu2f(cvb[(size_t)(tok0 + l) * CONVDIM + h * HEADDIM + p]);
        sXT[p * 88 + l] = f2bfu(sW[l] * v);
    }
    for (int i = t; i < 128 * 64; i += 256) {
        const int l = i >> 7, n = i & 127;
        sBT[n * 88 + l] = cvb[(size_t)(tok0 + l) * CONVDIM + DINNER + n];
    }
    __syncthreads();

    // S = X^T(w) @ B : 64 x 128, K = 64
    f32x4 acc[2][4];
    #pragma unroll
    for (int i = 0; i < 2; i++)
        #pragma unroll
        for (int j = 0; j < 4; j++)
            acc[i][j] = (f32x4){0.f, 0.f, 0.f, 0.f};
    #pragma unroll
    for (int k0 = 0; k0 < 64; k0 += 32) {
        bf16x8 af[2], bfv[4];
        #pragma unroll
        for (int i = 0; i < 2; i++)
            af[i] = *(const bf16x8*)&sXT[(wy * 32 + i * 16 + fr) * 88 + fk + k0];
        #pragma unroll
        for (int j = 0; j < 4; j++)
            bfv[j] = *(const bf16x8*)&sBT[(wx * 64 + j * 16 + fr) * 88 + fk + k0];
        #pragma unroll
        for (int i = 0; i < 2; i++)
            #pragma unroll
            for (int j = 0; j < 4; j++)
                acc[i][j] = __builtin_amdgcn_mfma_f32_16x16x32_bf16(
                    af[i], bfv[j], acc[i][j], 0, 0, 0);
    }
    const size_t slot = (size_t)(bh * NCHUNK + c) * 64 * 128;
    #pragma unroll
    for (int i = 0; i < 2; i++) {
        #pragma unroll
        for (int j = 0; j < 4; j++) {
            #pragma unroll
            for (int r = 0; r < 4; r++) {
                const int pr = wy * 32 + i * 16 + cr + r;
                const int nn = wx * 64 + j * 16 + fr;
                Sbuf[slot + pr * 128 + nn] = f2bfu(acc[i][j][r]);
            }
        }
    }
}

// Phase B: sequential stitch; writes incoming H_c into slot c.
__global__ __launch_bounds__(256) void stitch_kernel(
    const float* __restrict__ ccum, ushort_t* __restrict__ Sbuf)
{
    const int bh = blockIdx.x;
    const int t = threadIdx.x, p = t >> 2, q = t & 3;
    float H[32];
    #pragma unroll
    for (int j = 0; j < 32; j++) H[j] = 0.f;
    for (int c = 0; c < NCHUNK; c++) {
        const float P = expf(ccum[bh * NCHUNK + c]);
        const size_t slot = ((size_t)(bh * NCHUNK + c) * 64 + p) * 128;
        #pragma unroll
        for (int jj = 0; jj < 8; jj++) {
            const u16x4 sv4 = *(const u16x4*)&Sbuf[slot + q * 4 + 16 * jj];
            u16x4 hv4;
            #pragma unroll
            for (int k = 0; k < 4; k++) hv4[k] = f2bfu(H[jj * 4 + k]);
            *(u16x4*)&Sbuf[slot + q * 4 + 16 * jj] = hv4;
            #pragma unroll
            for (int k = 0; k < 4; k++)
                H[jj * 4 + k] = P * H[jj * 4 + k] + bfu2f(sv4[k]);
        }
    }
}

// Phase C (MFMA): Y = mask(C@B^T)@X + (exp(cum)*C)@H^T + D*X
// grid: 1024 = bh*16 + c
__global__ __launch_bounds__(256) void chunk_scan_mfma_kernel(
    const ushort_t* __restrict__ cvb, const float* __restrict__ dtb,
    const float* __restrict__ A_log, const float* __restrict__ Dh,
    const ushort_t* __restrict__ Sbuf, bf16* __restrict__ ybuf)
{
    const int bx = blockIdx.x;
    const int bh = bx >> 4, c = bx & 15;
    const int b = bh >> 5, h = bh & 31;
    const int t = threadIdx.x;
    const int w = t >> 6, lane = t & 63;
    const int wy = w >> 1, wx = w & 1;
    const int fr = lane & 15;
    const int fk = (lane >> 4) * 8;
    const int cr = (lane >> 4) * 4;
    const int tok0 = b * SEQLEN + c * Q;
    const float A = -expf(A_log[h]);
    const float Dv = Dh[h];

    __shared__ ushort_t sB[64 * 136];      // [l][n]
    __shared__ ushort_t sC[64 * 136];      // [l][n] (later scaled by exp(cum_l))
    __shared__ ushort_t sH[64 * 136];      // [p][n]
    __shared__ ushort_t sXT[64 * 72];      // [p][l]
    __shared__ ushort_t sM[64 * 72];       // [l][j]
    __shared__ float    sCum[64];
    __shared__ float    sDtv[64];

    // stage B, C (u16x4 copies from bf16 convb)
    for (int i = t; i < 64 * 32; i += 256) {
        const int row = i >> 5, col = (i & 31) * 4;
        const size_t base = (size_t)(tok0 + row) * CONVDIM;
        *(u16x4*)&sB[row * 136 + col] = *(const u16x4*)&cvb[base + DINNER + col];
        *(u16x4*)&sC[row * 136 + col] = *(const u16x4*)&cvb[base + DINNER + DSTATE + col];
    }
    // stage X transposed: sXT[p][l]
    for (int i = t; i < 64 * 32; i += 256) {
        const int p = i >> 5, l0 = (i & 31) * 2;
        const ushort_t x0 = cvb[(size_t)(tok0 + l0)     * CONVDIM + h * HEADDIM + p];
        const ushort_t x1 = cvb[(size_t)(tok0 + l0 + 1) * CONVDIM + h * HEADDIM + p];
        *(unsigned*)&sXT[p * 72 + l0] = ((unsigned)x1 << 16) | x0;
    }
    // stage H from Sbuf
    {
        const size_t slot = (size_t)(bh * NCHUNK + c) * 64 * 128;
        for (int i = t * 4; i < 64 * 128; i += 1024) {
            const int row = i >> 7, col = i & 127;
            *(u16x4*)&sH[row * 136 + col] = *(const u16x4*)&Sbuf[slot + row * 128 + col];
        }
    }
    // dt + inclusive cumsum (wave 0)
    if (t < 64) {
        const float d = dtb[(size_t)(tok0 + t) * NHEADS + h];
        float s = d;
        #pragma unroll
        for (int off = 1; off < 64; off <<= 1) {
            const float up = __shfl_up(s, off);
            if (t >= off) s += up;
        }
        sCum[t] = A * s;
        sDtv[t] = d;
    }
    __syncthreads();

    // GEMM1: G = C @ B^T  (l x j, K=n=128)
    f32x4 accg[2][2];
    #pragma unroll
    for (int i = 0; i < 2; i++)
        #pragma unroll
        for (int j = 0; j < 2; j++)
            accg[i][j] = (f32x4){0.f, 0.f, 0.f, 0.f};
    #pragma unroll
    for (int k0 = 0; k0 < 128; k0 += 32) {
        bf16x8 af[2], bfv[2];
        #pragma unroll
        for (int i = 0; i < 2; i++)
            af[i] = *(const bf16x8*)&sC[(wy * 32 + i * 16 + fr) * 136 + fk + k0];
        #pragma unroll
        for (int j = 0; j < 2; j++)
            bfv[j] = *(const bf16x8*)&sB[(wx * 32 + j * 16 + fr) * 136 + fk + k0];
        #pragma unroll
        for (int i = 0; i < 2; i++)
            #pragma unroll
            for (int j = 0; j < 2; j++)
                accg[i][j] = __builtin_amdgcn_mfma_f32_16x16x32_bf16(
                    af[i], bfv[j], accg[i][j], 0, 0, 0);
    }
    __syncthreads();   // all GEMM1 reads of sC done before scaling

    // write masked M to sM; scale sC rows by exp(cum_l)
    #pragma unroll
    for (int i = 0; i < 2; i++) {
        #pragma unroll
        for (int j = 0; j < 2; j++) {
            #pragma unroll
            for (int r = 0; r < 4; r++) {
                const int l  = wy * 32 + i * 16 + cr + r;
                const int jc = wx * 32 + j * 16 + fr;
                const float v = (jc <= l)
                    ? accg[i][j][r] * expf(sCum[l] - sCum[jc]) * sDtv[jc] : 0.f;
                sM[l * 72 + jc] = f2bfu(v);
            }
        }
    }
    for (int i = t; i < 64 * 32; i += 256) {
        const int row = i >> 5, col = (i & 31) * 4;
        const float sc = expf(sCum[row]);
        u16x4 v = *(const u16x4*)&sC[row * 136 + col];
        #pragma unroll
        for (int k = 0; k < 4; k++) v[k] = f2bfu(bfu2f(v[k]) * sc);
        *(u16x4*)&sC[row * 136 + col] = v;
    }
    __syncthreads();

    // GEMM2: Y = M @ X  +  (scaled C) @ H^T   (l x p)
    f32x4 accy[2][2];
    #pragma unroll
    for (int i = 0; i < 2; i++)
        #pragma unroll
        for (int j = 0; j < 2; j++)
            accy[i][j] = (f32x4){0.f, 0.f, 0.f, 0.f};
    #pragma unroll
    for (int k0 = 0; k0 < 64; k0 += 32) {
        bf16x8 af[2], bfv[2];
        #pragma unroll
        for (int i = 0; i < 2; i++)
            af[i] = *(const bf16x8*)&sM[(wy * 32 + i * 16 + fr) * 72 + fk + k0];
        #pragma unroll
        for (int j = 0; j < 2; j++)
            bfv[j] = *(const bf16x8*)&sXT[(wx * 32 + j * 16 + fr) * 72 + fk + k0];
        #pragma unroll
        for (int i = 0; i < 2; i++)
            #pragma unroll
            for (int j = 0; j < 2; j++)
                accy[i][j] = __builtin_amdgcn_mfma_f32_16x16x32_bf16(
                    af[i], bfv[j], accy[i][j], 0, 0, 0);
    }
    #pragma unroll
    for (int k0 = 0; k0 < 128; k0 += 32) {
        bf16x8 af[2], bfv[2];
        #pragma unroll
        for (int i = 0; i < 2; i++)
            af[i] = *(const bf16x8*)&sC[(wy * 32 + i * 16 + fr) * 136 + fk + k0];
        #pragma unroll
        for (int j = 0; j < 2; j++)
            bfv[j] = *(const bf16x8*)&sH[(wx * 32 + j * 16 + fr) * 136 + fk + k0];
        #pragma unroll
        for (int i = 0; i < 2; i++)
            #pragma unroll
            for (int j = 0; j < 2; j++)
                accy[i][j] = __builtin_amdgcn_mfma_f32_16x16x32_bf16(
                    af[i], bfv[j], accy[i][j], 0, 0, 0);
    }

    // epilogue: + D*x, store bf16
    #pragma unroll
    for (int i = 0; i < 2; i++) {
        #pragma unroll
        for (int j = 0; j < 2; j++) {
            #pragma unroll
            for (int r = 0; r < 4; r++) {
                const int l = wy * 32 + i * 16 + cr + r;
                const int p = wx * 32 + j * 16 + fr;
                const float x = bfu2f(sXT[p * 72 + l]);
                ybuf[(size_t)(tok0 + l) * DINNER + h * HEADDIM + p] =
                    __float2bfloat16(accy[i][j][r] + Dv * x);
            }
        }
    }
}

// ---- ynorm = rmsnorm(y * silu(z)) over 2048 dims -> bf16 (y is bf16) ----
__global__ __launch_bounds__(256) void gated_rmsnorm_kernel(
    const bf16* __restrict__ y, const float* __restrict__ zx,
    const float* __restrict__ w, bf16* __restrict__ out)
{
    const int token = blockIdx.x, t = threadIdx.x;
    const bf16* yr = y + (size_t)token * DINNER;
    const float* zr = zx + (size_t)token * DINPROJ;   // z = first 2048
    float v[8]; float ss = 0.f;
    #pragma unroll
    for (int i = 0; i < 8; i++) {
        const int idx = t * 8 + i;
        const float zz = zr[idx];
        const float val = bf2f(yr[idx]) * (zz / (1.f + expf(-zz)));
        v[i] = val; ss += val * val;
    }
    ss = block_reduce_sum(ss);
    const float scale = rsqrtf(ss * (1.0f / DINNER) + 1e-6f);
    #pragma unroll
    for (int i = 0; i < 8; i++) {
        const int idx = t * 8 + i;
        out[(size_t)token * DINNER + idx] =
            __float2bfloat16(v[i] * scale * w[idx]);
    }
}

// ---- act = bf16(silu(g) * u) from combined gu (2048 x 5504) ----
__global__ __launch_bounds__(256) void silu_mul_kernel(
    const float* __restrict__ gu, bf16* __restrict__ act, int n)
{
    const int i = blockIdx.x * 256 + threadIdx.x;
    if (i < n) {
        const int m = i / INTER, j = i - m * INTER;
        const float g = gu[(size_t)m * (2 * INTER) + j];
        const float u = gu[(size_t)m * (2 * INTER) + INTER + j];
        act[i] = __float2bfloat16((g / (1.f + expf(-g))) * u);
    }
}

extern "C" void kernel_launch(void* const* d_in, const int* in_sizes, int n_in,
                              void* d_out, int out_size, void* d_ws, size_t ws_size,
                              hipStream_t stream) {
    const float* hidden     = (const float*)d_in[0];
    const float* norm_w     = (const float*)d_in[1];
    const float* in_proj_w  = (const float*)d_in[2];
    const float* conv_w     = (const float*)d_in[3];
    const float* conv_b     = (const float*)d_in[4];
    const float* dt_bias    = (const float*)d_in[5];
    const float* A_log      = (const float*)d_in[6];
    const float* Dh         = (const float*)d_in[7];
    const float* ssm_norm_w = (const float*)d_in[8];
    const float* out_proj_w = (const float*)d_in[9];
    const float* post_norm_w= (const float*)d_in[10];
    const float* gate_w     = (const float*)d_in[11];
    const float* up_w       = (const float*)d_in[12];
    const float* down_w     = (const float*)d_in[13];
    float* out = (float*)d_out;

    // ---- workspace layout (fl units; peak = 23,200,768 fl = 92.8 MB) ----
    float* ws = (float*)d_ws;
    bf16*  h_norm = (bf16*)(ws);                 // [0, 1,048,576)
    float* zx     = ws + 1048576;                // [1,048,576, 10,027,008)
    ushort_t* cvb = (ushort_t*)(ws + 10027008);  // bf16 2048x2304 -> 2,359,296 fl
    float* dtb    = ws + 14745600;               // [14,745,600, 14,811,136)
    float* ccum   = ws + 14811136;               // 1024 fl
    ushort_t* Sbuf= (ushort_t*)(ws + 14812160);  // [14,812,160, 19,006,464) bf16
    float* xbuf   = ws + 19006464;               // [19,006,464, 21,103,616)
    bf16*  ybuf   = (bf16*)(ws + 21103616);      // [21,103,616, 22,152,192)
    bf16*  ynorm  = (bf16*)(ws + 22152192);      // [22,152,192, 23,200,768)
    // just-in-time bf16 weights in dead regions:
    ushort_t* Wip = (ushort_t*)(ws + 10027008);  // cvb region, dead before conv
    ushort_t* Wop = (ushort_t*)(ws + 1048576);   // zx region, after z consumed
    ushort_t* Wgu = (ushort_t*)(ws + 2097152);   // gate rows 0..2751, up 2752..5503
    ushort_t* Wdn = (ushort_t*)(ws + 4915200);
    float* gu     = ws + 6324224;                // [6,324,224, 17,596,416) f32 2048x5504
    bf16*  h2     = h_norm;                      // reuse
    bf16*  act    = (bf16*)(ws + 1048576);       // over Wop region (dead by then)

    // 0a. Wip = bf16(in_proj_w)
    f2bf_kernel<<<4384, 256, 0, stream>>>(in_proj_w, Wip, DINPROJ * DMODEL);
    // 1. h = rmsnorm(hidden, norm_w)  -> bf16
    rmsnorm1024_kernel<<<NTOK, 256, 0, stream>>>(hidden, norm_w, h_norm);
    // 2. zxbcdt = h @ Wip^T   (f32 out)
    gemm_bf<0, 128><<<dim3(35, 16), 256, 0, stream>>>(h_norm, (const bf16*)Wip, zx,
        nullptr, NTOK, DINPROJ, DMODEL);
    // 3. conv(k=4) + bias + silu on xBC -> bf16
    conv_silu_kernel<<<(NTOK * CONVDIM) / 256, 256, 0, stream>>>(zx, conv_w, conv_b, cvb);
    // 4. dt = softplus(dt_raw + dt_bias)
    dt_softplus_kernel<<<(NTOK * NHEADS) / 256, 256, 0, stream>>>(zx, dt_bias, dtb);
    // 5. chunked selective scan -> ybuf (bf16)
    chunk_state_kernel<<<1024, 256, 0, stream>>>(cvb, dtb, A_log, ccum, Sbuf);
    stitch_kernel<<<64, 256, 0, stream>>>(ccum, Sbuf);
    chunk_scan_mfma_kernel<<<1024, 256, 0, stream>>>(cvb, dtb, A_log, Dh, Sbuf, ybuf);
    // 6. ynorm = rmsnorm(y * silu(z), ssm_norm_w)  -> bf16 (last use of zx)
    gated_rmsnorm_kernel<<<NTOK, 256, 0, stream>>>(ybuf, zx, ssm_norm_w, ynorm);
    // 6b. convert remaining weights into dead zx region
    f2bf_kernel<<<2048, 256, 0, stream>>>(out_proj_w, Wop, DMODEL * DINNER);
    f2bf_kernel<<<2752, 256, 0, stream>>>(gate_w, Wgu, INTER * DMODEL);
    f2bf_kernel<<<2752, 256, 0, stream>>>(up_w, Wgu + INTER * DMODEL, INTER * DMODEL);
    f2bf_kernel<<<2752, 256, 0, stream>>>(down_w, Wdn, DMODEL * INTER);
    // 7. x = hidden + ynorm @ Wop^T  (f32), MT=64 tile -> 256 blocks
    gemm_bf<1, 64><<<dim3(8, 32), 256, 0, stream>>>(ynorm, (const bf16*)Wop, xbuf,
        hidden, NTOK, DMODEL, DINNER);
    // 8. h2 = rmsnorm(x, post_norm_w)  -> bf16
    rmsnorm1024_kernel<<<NTOK, 256, 0, stream>>>(xbuf, post_norm_w, h2);
    // 9. gu = h2 @ Wgu^T  (fused gate+up, N=5504)
    gemm_bf<0, 128><<<dim3(43, 16), 256, 0, stream>>>(h2, (const bf16*)Wgu, gu,
        nullptr, NTOK, 2 * INTER, DMODEL);
    // 10. act = bf16(silu(g) * u)
    silu_mul_kernel<<<(NTOK * INTER) / 256, 256, 0, stream>>>(gu, act, NTOK * INTER);
    // 11. out = x + act @ Wdn^T   (f32 to d_out), MT=64 tile
    gemm_bf<1, 64><<<dim3(8, 32), 256, 0, stream>>>(act, (const bf16*)Wdn, out,
        xbuf, NTOK, DMODEL, INTER);
}

// Round 11
// 378.950 us; speedup vs baseline: 7.5401x; 1.0849x over previous
//
#include <hip/hip_runtime.h>
#include <hip/hip_bf16.h>

// ---- problem constants ----
#define SEQLEN   1024
#define NTOK     2048          // BATCH * SEQLEN
#define DMODEL   1024
#define DSTATE   128
#define DINNER   2048
#define NHEADS   32
#define HEADDIM  64
#define CONVDIM  2304          // DINNER + 2*DSTATE
#define DINPROJ  4384          // 2*DINNER + 2*DSTATE + NHEADS
#define INTER    2752
#define Q        64            // scan chunk length
#define NCHUNK   16            // SEQLEN / Q

typedef __hip_bfloat16 bf16;
typedef unsigned short ushort_t;
typedef __attribute__((ext_vector_type(8))) short bf16x8;
typedef __attribute__((ext_vector_type(4))) float f32x4;
typedef __attribute__((ext_vector_type(4))) unsigned short u16x4;

__device__ __forceinline__ float bf2f(bf16 x) { return __bfloat162float(x); }
__device__ __forceinline__ float bfu2f(ushort_t u) {
    return __uint_as_float(((unsigned)u) << 16);
}
__device__ __forceinline__ ushort_t f2bfu(float x) {
    union { bf16 h; ushort_t u; } c; c.h = __float2bfloat16(x); return c.u;
}

__device__ __forceinline__ void glds16(const void* g, void* l) {
    __builtin_amdgcn_global_load_lds(
        (const __attribute__((address_space(1))) void*)g,
        (__attribute__((address_space(3))) void*)l, 16, 0, 0);
}

__device__ inline float block_reduce_sum(float v) {
    __shared__ float red[4];
    #pragma unroll
    for (int off = 32; off >= 1; off >>= 1) v += __shfl_down(v, off);
    int lane = threadIdx.x & 63, w = threadIdx.x >> 6;
    if (lane == 0) red[w] = v;
    __syncthreads();
    return red[0] + red[1] + red[2] + red[3];
}

// ---- fp32 -> bf16 weight convert (4 elems/thread) ----
__global__ __launch_bounds__(256) void f2bf_kernel(
    const float* __restrict__ src, ushort_t* __restrict__ dst, int n)
{
    const int i = (blockIdx.x * 256 + threadIdx.x) * 4;
    if (i < n) {
        const f32x4 v = *(const f32x4*)(src + i);
        u16x4 o;
        #pragma unroll
        for (int k = 0; k < 4; k++) o[k] = f2bfu(v[k]);
        *(u16x4*)(dst + i) = o;
    }
}

// ---- fused convert of out_proj / gate(interleave even) / up(odd) / down ----
#define NWOP (DMODEL * DINNER)     // 2,097,152
#define NWG  (INTER * DMODEL)      // 2,818,048
__global__ __launch_bounds__(256) void convert_weights_kernel(
    const float* __restrict__ wop, const float* __restrict__ wg,
    const float* __restrict__ wu, const float* __restrict__ wd,
    ushort_t* __restrict__ dWop, ushort_t* __restrict__ dWgu,
    ushort_t* __restrict__ dWdn)
{
    const int i4 = (blockIdx.x * 256 + threadIdx.x) * 4;
    const float* src;
    ushort_t* dst;
    if (i4 < NWOP) { src = wop + i4; dst = dWop + i4; }
    else if (i4 < NWOP + NWG) {
        const int e = i4 - NWOP, row = e >> 10, col = e & 1023;
        src = wg + e; dst = dWgu + ((size_t)(2 * row) << 10) + col;
    } else if (i4 < NWOP + 2 * NWG) {
        const int e = i4 - NWOP - NWG, row = e >> 10, col = e & 1023;
        src = wu + e; dst = dWgu + ((size_t)(2 * row + 1) << 10) + col;
    } else if (i4 < NWOP + 3 * NWG) {
        const int e = i4 - NWOP - 2 * NWG;
        src = wd + e; dst = dWdn + e;
    } else return;
    const f32x4 v = *(const f32x4*)src;
    u16x4 o;
    #pragma unroll
    for (int k = 0; k < 4; k++) o[k] = f2bfu(v[k]);
    *(u16x4*)dst = o;
}

// ---- RMSNorm over 1024 dims (fp32 in, fp32 weights) -> bf16 out ----
__global__ __launch_bounds__(256) void rmsnorm1024_kernel(
    const float* __restrict__ x, const float* __restrict__ w, bf16* __restrict__ out)
{
    const int token = blockIdx.x, t = threadIdx.x;
    float v[4]; float ss = 0.f;
    #pragma unroll
    for (int i = 0; i < 4; i++) {
        v[i] = x[(size_t)token * DMODEL + t * 4 + i];
        ss += v[i] * v[i];
    }
    ss = block_reduce_sum(ss);
    const float scale = rsqrtf(ss * (1.0f / DMODEL) + 1e-6f);
    #pragma unroll
    for (int i = 0; i < 4; i++)
        out[(size_t)token * DMODEL + t * 4 + i] =
            __float2bfloat16(v[i] * scale * w[t * 4 + i]);
}

// ---- MFMA GEMM (async staging): MT x NT tile, BK=32, 256 thr (2x2 waves) ----
// EPI 0: Cf=acc ; EPI 1: Cf=acc+resid_f ; EPI 2: swiglu -> out_bf (interleaved W)
template <int EPI, int MT, int NT>
__global__ __launch_bounds__(256) void gemm_bf(
    const bf16* __restrict__ A, const bf16* __restrict__ W,
    float* __restrict__ Cf, const float* __restrict__ resid_f,
    bf16* __restrict__ out_bf, int M, int N, int K)
{
    __shared__ ushort_t As[MT * 32];
    __shared__ ushort_t Bs[NT * 32];
    const int tid = threadIdx.x;
    const int w = tid >> 6, lane = tid & 63;
    const int m0 = blockIdx.y * MT, n0 = blockIdx.x * NT;

    const int srow = tid >> 2;          // 0..63
    const int skof = (tid & 3) * 8;
    const bf16* Ag0 = A + (size_t)(m0 + srow) * K + skof;
    const bf16* Ag1 = Ag0 + (size_t)64 * K;          // only if MT==128
    const int nr0 = n0 + srow, nr1 = n0 + 64 + srow;
    const bf16* Wg0 = W + (size_t)(nr0 < N ? nr0 : 0) * K + skof;
    const bf16* Wg1 = W + (size_t)((NT == 128 && nr1 < N) ? nr1 : 0) * K + skof;
    ushort_t* lA0 = &As[w * 512];
    ushort_t* lA1 = &As[2048 + w * 512];
    ushort_t* lB0 = &Bs[w * 512];
    ushort_t* lB1 = &Bs[2048 + w * 512];

    const int wy = w >> 1, wx = w & 1;
    const int fr = lane & 15;
    const int fk = (lane >> 4) * 8;
    constexpr int MI = MT / 32;
    constexpr int NJ = NT / 32;
    f32x4 acc[MI][NJ];
    #pragma unroll
    for (int i = 0; i < MI; i++)
        #pragma unroll
        for (int j = 0; j < NJ; j++)
            acc[i][j] = (f32x4){0.f, 0.f, 0.f, 0.f};

    for (int k0 = 0; k0 < K; k0 += 32) {
        __syncthreads();
        glds16(Ag0 + k0, lA0);
        if (MT == 128) glds16(Ag1 + k0, lA1);
        glds16(Wg0 + k0, lB0);
        if (NT == 128) glds16(Wg1 + k0, lB1);
        __syncthreads();
        bf16x8 af[MI], bfv[NJ];
        #pragma unroll
        for (int i = 0; i < MI; i++)
            af[i] = *(const bf16x8*)&As[(wy * (MT / 2) + i * 16 + fr) * 32 + fk];
        #pragma unroll
        for (int j = 0; j < NJ; j++)
            bfv[j] = *(const bf16x8*)&Bs[(wx * (NT / 2) + j * 16 + fr) * 32 + fk];
        #pragma unroll
        for (int i = 0; i < MI; i++)
            #pragma unroll
            for (int j = 0; j < NJ; j++)
                acc[i][j] = __builtin_amdgcn_mfma_f32_16x16x32_bf16(
                    af[i], bfv[j], acc[i][j], 0, 0, 0);
    }

    // C/D layout: col = lane&15, row = (lane>>4)*4 + reg
    #pragma unroll
    for (int i = 0; i < MI; i++) {
        #pragma unroll
        for (int j = 0; j < NJ; j++) {
            const int mb = m0 + wy * (MT / 2) + i * 16 + (lane >> 4) * 4;
            const int nn = n0 + wx * (NT / 2) + j * 16 + (lane & 15);
            if (nn < N) {
                #pragma unroll
                for (int r = 0; r < 4; r++) {
                    if (EPI == 2) {
                        // interleaved: even col = gate, odd col = up
                        const float g = acc[i][j][r];
                        const float u = __shfl_xor(g, 1);
                        if (!(lane & 1)) {
                            const float a = (g / (1.f + expf(-g))) * u;
                            out_bf[(size_t)(mb + r) * (N / 2) + (nn >> 1)] =
                                __float2bfloat16(a);
                        }
                    } else {
                        const size_t idx = (size_t)(mb + r) * N + nn;
                        float v = acc[i][j][r];
                        if (EPI == 1) v += resid_f[idx];
                        Cf[idx] = v;
                    }
                }
            }
        }
    }
}

// ---- depthwise causal conv (k=4) + bias + silu over xBC -> bf16 out ----
__global__ __launch_bounds__(256) void conv_silu_kernel(
    const float* __restrict__ zx, const float* __restrict__ cw,
    const float* __restrict__ cb, ushort_t* __restrict__ out)
{
    const int idx = blockIdx.x * 256 + threadIdx.x;
    if (idx >= NTOK * CONVDIM) return;
    const int c = idx % CONVDIM;
    const int token = idx / CONVDIM;
    const int l = token & (SEQLEN - 1);
    float acc = cb[c];
    #pragma unroll
    for (int k = 0; k < 4; k++) {
        const int ls = l - 3 + k;
        if (ls >= 0)
            acc += zx[(size_t)(token - 3 + k) * DINPROJ + DINNER + c] * cw[c * 4 + k];
    }
    out[(size_t)token * CONVDIM + c] = f2bfu(acc / (1.f + expf(-acc)));   // silu
}

// ---- dt = softplus(dt_raw + dt_bias) ----
__global__ __launch_bounds__(256) void dt_softplus_kernel(
    const float* __restrict__ zx, const float* __restrict__ dtb,
    float* __restrict__ out)
{
    const int idx = blockIdx.x * 256 + threadIdx.x;   // NTOK*NHEADS
    const int h = idx & (NHEADS - 1);
    const int token = idx >> 5;
    float v = zx[(size_t)token * DINPROJ + (DINNER + CONVDIM) + h] + dtb[h];
    out[idx] = (v > 20.f) ? v : log1pf(expf(v));
}

// ================= chunked scan =================
// Phase A (MFMA): S[p,n] = sum_l (w_l x[l,p]) B[l,n],  w_l = exp(cumQ-cum_l)*dt_l
__global__ __launch_bounds__(256) void chunk_state_kernel(
    const ushort_t* __restrict__ cvb, const float* __restrict__ dtb,
    const float* __restrict__ A_log, float* __restrict__ ccum,
    ushort_t* __restrict__ Sbuf)
{
    const int bx = blockIdx.x;
    const int bh = bx >> 4, c = bx & 15;
    const int b = bh >> 5, h = bh & 31;
    const int t = threadIdx.x;
    const int w = t >> 6, lane = t & 63;
    const int wy = w >> 1, wx = w & 1;
    const int fr = lane & 15, fk = (lane >> 4) * 8, cr = (lane >> 4) * 4;
    const int tok0 = b * SEQLEN + c * Q;
    const float A = -expf(A_log[h]);

    __shared__ ushort_t sXT[64 * 88];    // [p][l], weighted
    __shared__ ushort_t sBT[128 * 88];   // [n][l]
    __shared__ float sW[64];

    if (t < 64) {
        const float d = dtb[(size_t)(tok0 + t) * NHEADS + h];
        float s = d;
        #pragma unroll
        for (int off = 1; off < 64; off <<= 1) {
            const float up = __shfl_up(s, off);
            if (t >= off) s += up;
        }
        const float total = __shfl(s, 63);
        sW[t] = expf(A * (total - s)) * d;     // arg <= 0
        if (t == 63) ccum[bh * NCHUNK + c] = A * total;
    }
    __syncthreads();

    for (int i = t; i < 64 * 64; i += 256) {
        const int l = i >> 6, p = i & 63;
        const float v = bfu2f(cvb[(size_t)(tok0 + l) * CONVDIM + h * HEADDIM + p]);
        sXT[p * 88 + l] = f2bfu(sW[l] * v);
    }
    for (int i = t; i < 128 * 64; i += 256) {
        const int l = i >> 7, n = i & 127;
        sBT[n * 88 + l] = cvb[(size_t)(tok0 + l) * CONVDIM + DINNER + n];
    }
    __syncthreads();

    f32x4 acc[2][4];
    #pragma unroll
    for (int i = 0; i < 2; i++)
        #pragma unroll
        for (int j = 0; j < 4; j++)
            acc[i][j] = (f32x4){0.f, 0.f, 0.f, 0.f};
    #pragma unroll
    for (int k0 = 0; k0 < 64; k0 += 32) {
        bf16x8 af[2], bfv[4];
        #pragma unroll
        for (int i = 0; i < 2; i++)
            af[i] = *(const bf16x8*)&sXT[(wy * 32 + i * 16 + fr) * 88 + fk + k0];
        #pragma unroll
        for (int j = 0; j < 4; j++)
            bfv[j] = *(const bf16x8*)&sBT[(wx * 64 + j * 16 + fr) * 88 + fk + k0];
        #pragma unroll
        for (int i = 0; i < 2; i++)
            #pragma unroll
            for (int j = 0; j < 4; j++)
                acc[i][j] = __builtin_amdgcn_mfma_f32_16x16x32_bf16(
                    af[i], bfv[j], acc[i][j], 0, 0, 0);
    }
    const size_t slot = (size_t)(bh * NCHUNK + c) * 64 * 128;
    #pragma unroll
    for (int i = 0; i < 2; i++) {
        #pragma unroll
        for (int j = 0; j < 4; j++) {
            #pragma unroll
            for (int r = 0; r < 4; r++) {
                const int pr = wy * 32 + i * 16 + cr + r;
                const int nn = wx * 64 + j * 16 + fr;
                Sbuf[slot + pr * 128 + nn] = f2bfu(acc[i][j][r]);
            }
        }
    }
}

// Phase B: sequential stitch; writes incoming H_c into slot c.
__global__ __launch_bounds__(256) void stitch_kernel(
    const float* __restrict__ ccum, ushort_t* __restrict__ Sbuf)
{
    const int bh = blockIdx.x;
    const int t = threadIdx.x, p = t >> 2, q = t & 3;
    float H[32];
    #pragma unroll
    for (int j = 0; j < 32; j++) H[j] = 0.f;
    for (int c = 0; c < NCHUNK; c++) {
        const float P = expf(ccum[bh * NCHUNK + c]);
        const size_t slot = ((size_t)(bh * NCHUNK + c) * 64 + p) * 128;
        #pragma unroll
        for (int jj = 0; jj < 8; jj++) {
            const u16x4 sv4 = *(const u16x4*)&Sbuf[slot + q * 4 + 16 * jj];
            u16x4 hv4;
            #pragma unroll
            for (int k = 0; k < 4; k++) hv4[k] = f2bfu(H[jj * 4 + k]);
            *(u16x4*)&Sbuf[slot + q * 4 + 16 * jj] = hv4;
            #pragma unroll
            for (int k = 0; k < 4; k++)
                H[jj * 4 + k] = P * H[jj * 4 + k] + bfu2f(sv4[k]);
        }
    }
}

// Phase C (MFMA): Y = mask(C@B^T)@X + (exp(cum)*C)@H^T + D*X
__global__ __launch_bounds__(256) void chunk_scan_mfma_kernel(
    const ushort_t* __restrict__ cvb, const float* __restrict__ dtb,
    const float* __restrict__ A_log, const float* __restrict__ Dh,
    const ushort_t* __restrict__ Sbuf, bf16* __restrict__ ybuf)
{
    const int bx = blockIdx.x;
    const int bh = bx >> 4, c = bx & 15;
    const int b = bh >> 5, h = bh & 31;
    const int t = threadIdx.x;
    const int w = t >> 6, lane = t & 63;
    const int wy = w >> 1, wx = w & 1;
    const int fr = lane & 15;
    const int fk = (lane >> 4) * 8;
    const int cr = (lane >> 4) * 4;
    const int tok0 = b * SEQLEN + c * Q;
    const float A = -expf(A_log[h]);
    const float Dv = Dh[h];

    __shared__ ushort_t sB[64 * 136];
    __shared__ ushort_t sC[64 * 136];
    __shared__ ushort_t sH[64 * 136];
    __shared__ ushort_t sXT[64 * 72];
    __shared__ ushort_t sM[64 * 72];
    __shared__ float    sCum[64];
    __shared__ float    sDtv[64];

    for (int i = t; i < 64 * 32; i += 256) {
        const int row = i >> 5, col = (i & 31) * 4;
        const size_t base = (size_t)(tok0 + row) * CONVDIM;
        *(u16x4*)&sB[row * 136 + col] = *(const u16x4*)&cvb[base + DINNER + col];
        *(u16x4*)&sC[row * 136 + col] = *(const u16x4*)&cvb[base + DINNER + DSTATE + col];
    }
    for (int i = t; i < 64 * 32; i += 256) {
        const int p = i >> 5, l0 = (i & 31) * 2;
        const ushort_t x0 = cvb[(size_t)(tok0 + l0)     * CONVDIM + h * HEADDIM + p];
        const ushort_t x1 = cvb[(size_t)(tok0 + l0 + 1) * CONVDIM + h * HEADDIM + p];
        *(unsigned*)&sXT[p * 72 + l0] = ((unsigned)x1 << 16) | x0;
    }
    {
        const size_t slot = (size_t)(bh * NCHUNK + c) * 64 * 128;
        for (int i = t * 4; i < 64 * 128; i += 1024) {
            const int row = i >> 7, col = i & 127;
            *(u16x4*)&sH[row * 136 + col] = *(const u16x4*)&Sbuf[slot + row * 128 + col];
        }
    }
    if (t < 64) {
        const float d = dtb[(size_t)(tok0 + t) * NHEADS + h];
        float s = d;
        #pragma unroll
        for (int off = 1; off < 64; off <<= 1) {
            const float up = __shfl_up(s, off);
            if (t >= off) s += up;
        }
        sCum[t] = A * s;
        sDtv[t] = d;
    }
    __syncthreads();

    // GEMM1: G = C @ B^T
    f32x4 accg[2][2];
    #pragma unroll
    for (int i = 0; i < 2; i++)
        #pragma unroll
        for (int j = 0; j < 2; j++)
            accg[i][j] = (f32x4){0.f, 0.f, 0.f, 0.f};
    #pragma unroll
    for (int k0 = 0; k0 < 128; k0 += 32) {
        bf16x8 af[2], bfv[2];
        #pragma unroll
        for (int i = 0; i < 2; i++)
            af[i] = *(const bf16x8*)&sC[(wy * 32 + i * 16 + fr) * 136 + fk + k0];
        #pragma unroll
        for (int j = 0; j < 2; j++)
            bfv[j] = *(const bf16x8*)&sB[(wx * 32 + j * 16 + fr) * 136 + fk + k0];
        #pragma unroll
        for (int i = 0; i < 2; i++)
            #pragma unroll
            for (int j = 0; j < 2; j++)
                accg[i][j] = __builtin_amdgcn_mfma_f32_16x16x32_bf16(
                    af[i], bfv[j], accg[i][j], 0, 0, 0);
    }
    __syncthreads();

    #pragma unroll
    for (int i = 0; i < 2; i++) {
        #pragma unroll
        for (int j = 0; j < 2; j++) {
            #pragma unroll
            for (int r = 0; r < 4; r++) {
                const int l  = wy * 32 + i * 16 + cr + r;
                const int jc = wx * 32 + j * 16 + fr;
                const float v = (jc <= l)
                    ? accg[i][j][r] * expf(sCum[l] - sCum[jc]) * sDtv[jc] : 0.f;
                sM[l * 72 + jc] = f2bfu(v);
            }
        }
    }
    for (int i = t; i < 64 * 32; i += 256) {
        const int row = i >> 5, col = (i & 31) * 4;
        const float sc = expf(sCum[row]);
        u16x4 v = *(const u16x4*)&sC[row * 136 + col];
        #pragma unroll
        for (int k = 0; k < 4; k++) v[k] = f2bfu(bfu2f(v[k]) * sc);
        *(u16x4*)&sC[row * 136 + col] = v;
    }
    __syncthreads();

    // GEMM2: Y = M @ X + (scaled C) @ H^T
    f32x4 accy[2][2];
    #pragma unroll
    for (int i = 0; i < 2; i++)
        #pragma unroll
        for (int j = 0; j < 2; j++)
            accy[i][j] = (f32x4){0.f, 0.f, 0.f, 0.f};
    #pragma unroll
    for (int k0 = 0; k0 < 64; k0 += 32) {
        bf16x8 af[2], bfv[2];
        #pragma unroll
        for (int i = 0; i < 2; i++)
            af[i] = *(const bf16x8*)&sM[(wy * 32 + i * 16 + fr) * 72 + fk + k0];
        #pragma unroll
        for (int j = 0; j < 2; j++)
            bfv[j] = *(const bf16x8*)&sXT[(wx * 32 + j * 16 + fr) * 72 + fk + k0];
        #pragma unroll
        for (int i = 0; i < 2; i++)
            #pragma unroll
            for (int j = 0; j < 2; j++)
                accy[i][j] = __builtin_amdgcn_mfma_f32_16x16x32_bf16(
                    af[i], bfv[j], accy[i][j], 0, 0, 0);
    }
    #pragma unroll
    for (int k0 = 0; k0 < 128; k0 += 32) {
        bf16x8 af[2], bfv[2];
        #pragma unroll
        for (int i = 0; i < 2; i++)
            af[i] = *(const bf16x8*)&sC[(wy * 32 + i * 16 + fr) * 136 + fk + k0];
        #pragma unroll
        for (int j = 0; j < 2; j++)
            bfv[j] = *(const bf16x8*)&sH[(wx * 32 + j * 16 + fr) * 136 + fk + k0];
        #pragma unroll
        for (int i = 0; i < 2; i++)
            #pragma unroll
            for (int j = 0; j < 2; j++)
                accy[i][j] = __builtin_amdgcn_mfma_f32_16x16x32_bf16(
                    af[i], bfv[j], accy[i][j], 0, 0, 0);
    }

    #pragma unroll
    for (int i = 0; i < 2; i++) {
        #pragma unroll
        for (int j = 0; j < 2; j++) {
            #pragma unroll
            for (int r = 0; r < 4; r++) {
                const int l = wy * 32 + i * 16 + cr + r;
                const int p = wx * 32 + j * 16 + fr;
                const float x = bfu2f(sXT[p * 72 + l]);
                ybuf[(size_t)(tok0 + l) * DINNER + h * HEADDIM + p] =
                    __float2bfloat16(accy[i][j][r] + Dv * x);
            }
        }
    }
}

// ---- ynorm = rmsnorm(y * silu(z)) over 2048 dims -> bf16 (y is bf16) ----
__global__ __launch_bounds__(256) void gated_rmsnorm_kernel(
    const bf16* __restrict__ y, const float* __restrict__ zx,
    const float* __restrict__ w, bf16* __restrict__ out)
{
    const int token = blockIdx.x, t = threadIdx.x;
    const bf16* yr = y + (size_t)token * DINNER;
    const float* zr = zx + (size_t)token * DINPROJ;   // z = first 2048
    float v[8]; float ss = 0.f;
    #pragma unroll
    for (int i = 0; i < 8; i++) {
        const int idx = t * 8 + i;
        const float zz = zr[idx];
        const float val = bf2f(yr[idx]) * (zz / (1.f + expf(-zz)));
        v[i] = val; ss += val * val;
    }
    ss = block_reduce_sum(ss);
    const float scale = rsqrtf(ss * (1.0f / DINNER) + 1e-6f);
    #pragma unroll
    for (int i = 0; i < 8; i++) {
        const int idx = t * 8 + i;
        out[(size_t)token * DINNER + idx] =
            __float2bfloat16(v[i] * scale * w[idx]);
    }
}

extern "C" void kernel_launch(void* const* d_in, const int* in_sizes, int n_in,
                              void* d_out, int out_size, void* d_ws, size_t ws_size,
                              hipStream_t stream) {
    const float* hidden     = (const float*)d_in[0];
    const float* norm_w     = (const float*)d_in[1];
    const float* in_proj_w  = (const float*)d_in[2];
    const float* conv_w     = (const float*)d_in[3];
    const float* conv_b     = (const float*)d_in[4];
    const float* dt_bias    = (const float*)d_in[5];
    const float* A_log      = (const float*)d_in[6];
    const float* Dh         = (const float*)d_in[7];
    const float* ssm_norm_w = (const float*)d_in[8];
    const float* out_proj_w = (const float*)d_in[9];
    const float* post_norm_w= (const float*)d_in[10];
    const float* gate_w     = (const float*)d_in[11];
    const float* up_w       = (const float*)d_in[12];
    const float* down_w     = (const float*)d_in[13];
    float* out = (float*)d_out;

    // ---- workspace layout (fl units; peak = 23,200,768 fl = 92.8 MB) ----
    float* ws = (float*)d_ws;
    bf16*  h_norm = (bf16*)(ws);                 // [0, 1,048,576)
    float* zx     = ws + 1048576;                // [1,048,576, 10,027,008)
    ushort_t* cvb = (ushort_t*)(ws + 10027008);  // bf16 2048x2304
    float* dtb    = ws + 14745600;               // [14,745,600, 14,811,136)
    float* ccum   = ws + 14811136;               // 1024 fl
    ushort_t* Sbuf= (ushort_t*)(ws + 14812160);  // [14,812,160, 19,006,464) bf16
    float* xbuf   = ws + 19006464;               // [19,006,464, 21,103,616)
    bf16*  ybuf   = (bf16*)(ws + 21103616);      // [21,103,616, 22,152,192)
    bf16*  ynorm  = (bf16*)(ws + 22152192);      // [22,152,192, 23,200,768)
    // just-in-time bf16 weights in dead regions (zx dead after step 6):
    ushort_t* Wip = (ushort_t*)(ws + 10027008);  // cvb region, dead before conv
    ushort_t* Wop = (ushort_t*)(ws + 1048576);   // [1,048,576, 2,097,152)
    ushort_t* Wgu = (ushort_t*)(ws + 2097152);   // interleaved gate/up [.., 4,915,200)
    ushort_t* Wdn = (ushort_t*)(ws + 4915200);   // [4,915,200, 6,324,224)
    bf16*  act    = (bf16*)(ws + 6324224);       // [6,324,224, 9,142,272) bf16 2048x2752
    bf16*  h2     = h_norm;                      // reuse

    // 0a. Wip = bf16(in_proj_w)
    f2bf_kernel<<<4384, 256, 0, stream>>>(in_proj_w, Wip, DINPROJ * DMODEL);
    // 1. h = rmsnorm(hidden, norm_w)  -> bf16
    rmsnorm1024_kernel<<<NTOK, 256, 0, stream>>>(hidden, norm_w, h_norm);
    // 2. zxbcdt = h @ Wip^T   (f32 out)
    gemm_bf<0, 128, 128><<<dim3(35, 16), 256, 0, stream>>>(h_norm, (const bf16*)Wip, zx,
        nullptr, nullptr, NTOK, DINPROJ, DMODEL);
    // 3. conv(k=4) + bias + silu on xBC -> bf16
    conv_silu_kernel<<<(NTOK * CONVDIM) / 256, 256, 0, stream>>>(zx, conv_w, conv_b, cvb);
    // 4. dt = softplus(dt_raw + dt_bias)
    dt_softplus_kernel<<<(NTOK * NHEADS) / 256, 256, 0, stream>>>(zx, dt_bias, dtb);
    // 5. chunked selective scan -> ybuf (bf16)
    chunk_state_kernel<<<1024, 256, 0, stream>>>(cvb, dtb, A_log, ccum, Sbuf);
    stitch_kernel<<<64, 256, 0, stream>>>(ccum, Sbuf);
    chunk_scan_mfma_kernel<<<1024, 256, 0, stream>>>(cvb, dtb, A_log, Dh, Sbuf, ybuf);
    // 6. ynorm = rmsnorm(y * silu(z), ssm_norm_w)  -> bf16 (last use of zx)
    gated_rmsnorm_kernel<<<NTOK, 256, 0, stream>>>(ybuf, zx, ssm_norm_w, ynorm);
    // 6b. convert out_proj/gate+up(interleaved)/down weights (fused)
    convert_weights_kernel<<<(NWOP + 3 * NWG) / 1024, 256, 0, stream>>>(
        out_proj_w, gate_w, up_w, down_w, Wop, Wgu, Wdn);
    // 7. x = hidden + ynorm @ Wop^T  (f32), 64x64 tiles -> 512 blocks
    gemm_bf<1, 64, 64><<<dim3(16, 32), 256, 0, stream>>>(ynorm, (const bf16*)Wop, xbuf,
        hidden, nullptr, NTOK, DMODEL, DINNER);
    // 8. h2 = rmsnorm(x, post_norm_w)  -> bf16
    rmsnorm1024_kernel<<<NTOK, 256, 0, stream>>>(xbuf, post_norm_w, h2);
    // 9+10. act = swiglu(h2 @ Wgu^T)  (fused epilogue, interleaved N=5504)
    gemm_bf<2, 128, 128><<<dim3(43, 16), 256, 0, stream>>>(h2, (const bf16*)Wgu,
        nullptr, nullptr, act, NTOK, 2 * INTER, DMODEL);
    // 11. out = x + act @ Wdn^T   (f32 to d_out), 64x64 tiles
    gemm_bf<1, 64, 64><<<dim3(16, 32), 256, 0, stream>>>(act, (const bf16*)Wdn, out,
        xbuf, nullptr, NTOK, DMODEL, INTER);
}